// Round 1
// baseline (5856.762 us; speedup 1.0000x reference)
//
#include <hip/hip_runtime.h>

// PerceiverResampler on MI355X (gfx950), bf16 MFMA implementation.
// All GEMMs: C = A(bf16, MxK row-major) @ B^T(bf16, NxK row-major), fp32 acc.
// Weights are cast+transposed to NxK bf16 per layer (buffers reused; stream-ordered).

typedef __attribute__((ext_vector_type(8))) short bf16x8;
typedef __attribute__((ext_vector_type(4))) float f32x4;
typedef unsigned int u32;
typedef unsigned short u16;

#define MFMA16(a, b, c) __builtin_amdgcn_mfma_f32_16x16x32_bf16((a), (b), (c), 0, 0, 0)

__device__ __forceinline__ u16 f2bf(float f) {
  u32 u = __builtin_bit_cast(u32, f);
  u = (u + 0x7fffu + ((u >> 16) & 1u)) >> 16;  // RNE; inputs finite
  return (u16)u;
}

__device__ __forceinline__ void gld_lds16(const void* g, void* l) {
  __builtin_amdgcn_global_load_lds(
      (const __attribute__((address_space(1))) u32*)g,
      (__attribute__((address_space(3))) u32*)l, 16, 0, 0);
}

// ---------------------------------------------------------------------------
// init: lat[bt*128+i][:] = latents[i][:]
__global__ __launch_bounds__(256) void init_lat(const float* __restrict__ latents,
                                                float* __restrict__ lat) {
  const int r = blockIdx.x;  // 0..4095
  ((float4*)(lat + (size_t)r * 1024))[threadIdx.x] =
      ((const float4*)(latents + (size_t)(r & 127) * 1024))[threadIdx.x];
}

// ---------------------------------------------------------------------------
// transpose-cast: W (KxN fp32) -> WT (NxK bf16), optional scalar scale
__global__ __launch_bounds__(256) void wcastT(const float* __restrict__ W,
                                              u16* __restrict__ WT, int K, int N,
                                              float scale) {
  __shared__ float tile[32][33];
  const int tx = threadIdx.x & 31;
  const int ty = threadIdx.x >> 5;  // 0..7
  const int n0 = blockIdx.x * 32;
  const int k0 = blockIdx.y * 32;
#pragma unroll
  for (int i = 0; i < 4; ++i)
    tile[ty + i * 8][tx] = W[(size_t)(k0 + ty + i * 8) * N + n0 + tx];
  __syncthreads();
#pragma unroll
  for (int i = 0; i < 4; ++i)
    WT[(size_t)(n0 + ty + i * 8) * K + k0 + tx] = f2bf(tile[tx][ty + i * 8] * scale);
}

// ---------------------------------------------------------------------------
// LayerNorm of a 1024-wide row -> bf16, with output row remap:
//   orow = (r/grp)*stride + off + (r%grp);  optional second plain-row output.
__global__ __launch_bounds__(256) void ln1024_bf16(
    const float* __restrict__ in, const float* __restrict__ g,
    const float* __restrict__ b, u16* __restrict__ out1, int grp, int stride,
    int off, u16* __restrict__ out2) {
  const int r = blockIdx.x;
  const int t = threadIdx.x;
  float4 xv = ((const float4*)(in + (size_t)r * 1024))[t];
  float s = xv.x + xv.y + xv.z + xv.w;
  float s2 = xv.x * xv.x + xv.y * xv.y + xv.z * xv.z + xv.w * xv.w;
#pragma unroll
  for (int d = 1; d < 64; d <<= 1) {
    s += __shfl_xor(s, d);
    s2 += __shfl_xor(s2, d);
  }
  __shared__ float red[8];
  const int w = t >> 6;
  if ((t & 63) == 0) {
    red[w] = s;
    red[4 + w] = s2;
  }
  __syncthreads();
  s = red[0] + red[1] + red[2] + red[3];
  s2 = red[4] + red[5] + red[6] + red[7];
  const float mu = s * (1.f / 1024.f);
  const float rs = rsqrtf(fmaxf(s2 * (1.f / 1024.f) - mu * mu, 0.f) + 1e-5f);
  float4 gv = ((const float4*)g)[t];
  float4 bv = ((const float4*)b)[t];
  ushort4 o;
  o.x = f2bf((xv.x - mu) * rs * gv.x + bv.x);
  o.y = f2bf((xv.y - mu) * rs * gv.y + bv.y);
  o.z = f2bf((xv.z - mu) * rs * gv.z + bv.z);
  o.w = f2bf((xv.w - mu) * rs * gv.w + bv.w);
  const size_t orow = (size_t)(r / grp) * stride + off + (r % grp);
  ((ushort4*)(out1 + orow * 1024))[t] = o;
  if (out2) ((ushort4*)(out2 + (size_t)r * 1024))[t] = o;
}

// final LN -> fp32 out
__global__ __launch_bounds__(256) void ln1024_f32(const float* __restrict__ in,
                                                  const float* __restrict__ g,
                                                  const float* __restrict__ b,
                                                  float* __restrict__ out) {
  const int r = blockIdx.x;
  const int t = threadIdx.x;
  float4 xv = ((const float4*)(in + (size_t)r * 1024))[t];
  float s = xv.x + xv.y + xv.z + xv.w;
  float s2 = xv.x * xv.x + xv.y * xv.y + xv.z * xv.z + xv.w * xv.w;
#pragma unroll
  for (int d = 1; d < 64; d <<= 1) {
    s += __shfl_xor(s, d);
    s2 += __shfl_xor(s2, d);
  }
  __shared__ float red[8];
  const int w = t >> 6;
  if ((t & 63) == 0) {
    red[w] = s;
    red[4 + w] = s2;
  }
  __syncthreads();
  s = red[0] + red[1] + red[2] + red[3];
  s2 = red[4] + red[5] + red[6] + red[7];
  const float mu = s * (1.f / 1024.f);
  const float rs = rsqrtf(fmaxf(s2 * (1.f / 1024.f) - mu * mu, 0.f) + 1e-5f);
  float4 gv = ((const float4*)g)[t];
  float4 bv = ((const float4*)b)[t];
  float4 o;
  o.x = (xv.x - mu) * rs * gv.x + bv.x;
  o.y = (xv.y - mu) * rs * gv.y + bv.y;
  o.z = (xv.z - mu) * rs * gv.z + bv.z;
  o.w = (xv.w - mu) * rs * gv.w + bv.w;
  ((float4*)(out + (size_t)r * 1024))[t] = o;
}

// ---------------------------------------------------------------------------
// GEMM: C(MxN) = A(MxK bf16) @ BT(NxK bf16)^T, m97-style 128x128 tile, BK=32.
// mode 0: bf16 out (ldc=N)        mode 1: gelu(exact) -> bf16 out
// mode 2: fp32 residual add       mode 3: KV split (K -> out0 ldc=1536,
//         V -> out1 transposed layout [bt][h][d][n], rows are bt*1152+n)
__global__ __launch_bounds__(256) void gemm_bt(const u16* __restrict__ A,
                                               const u16* __restrict__ BT, int M,
                                               int N, int K, int mode,
                                               void* __restrict__ out0,
                                               void* __restrict__ out1) {
  __shared__ u16 Alds[128 * 32];
  __shared__ u16 Blds[128 * 32];
  const int t = threadIdx.x;
  const int l = t & 63;
  const int w = t >> 6;
  const int m0 = blockIdx.y * 128;
  const int n0 = blockIdx.x * 128;
  const int wr = (w >> 1) * 64;
  const int wc = (w & 1) * 64;
  const int arow = t >> 2;        // staging row (per round)
  const int acol = (t & 3) * 8;   // staging k offset
  const int frow = l & 15;        // fragment row within 16
  const int fk = (l >> 4) * 8;    // fragment k offset

  f32x4 acc[4][4] = {};

  const u16* Ap = A + (size_t)(m0 + arow) * K + acol;
  const u16* Ap2 = A + (size_t)(m0 + 64 + arow) * K + acol;
  const u16* Bp = BT + (size_t)(n0 + arow) * K + acol;
  const u16* Bp2 = BT + (size_t)(n0 + 64 + arow) * K + acol;

  for (int k0 = 0; k0 < K; k0 += 32) {
    __syncthreads();
    gld_lds16(Ap + k0, &Alds[t * 8]);
    gld_lds16(Ap2 + k0, &Alds[2048 + t * 8]);
    gld_lds16(Bp + k0, &Blds[t * 8]);
    gld_lds16(Bp2 + k0, &Blds[2048 + t * 8]);
    __syncthreads();
    bf16x8 af[4], bfr[4];
#pragma unroll
    for (int i = 0; i < 4; ++i)
      af[i] = *(const bf16x8*)&Alds[(wr + i * 16 + frow) * 32 + fk];
#pragma unroll
    for (int j = 0; j < 4; ++j)
      bfr[j] = *(const bf16x8*)&Blds[(wc + j * 16 + frow) * 32 + fk];
#pragma unroll
    for (int i = 0; i < 4; ++i)
#pragma unroll
      for (int j = 0; j < 4; ++j) acc[i][j] = MFMA16(af[i], bfr[j], acc[i][j]);
  }

  const int col = l & 15;
  const int r4 = (l >> 4) * 4;
#pragma unroll
  for (int i = 0; i < 4; ++i) {
    const int row0 = m0 + wr + i * 16 + r4;
#pragma unroll
    for (int j = 0; j < 4; ++j) {
      const int c = n0 + wc + j * 16 + col;
      if (mode == 3) {
        if (c < 1536) {
          u16* Kb = (u16*)out0;
#pragma unroll
          for (int r = 0; r < 4; ++r)
            Kb[(size_t)(row0 + r) * 1536 + c] = f2bf(acc[i][j][r]);
        } else {
          const int cc = c - 1536;
          const int hh = cc / 96, dd = cc % 96;
          const int btq = row0 / 1152, nn = row0 % 1152;
          ushort4 pk;
          pk.x = f2bf(acc[i][j][0]);
          pk.y = f2bf(acc[i][j][1]);
          pk.z = f2bf(acc[i][j][2]);
          pk.w = f2bf(acc[i][j][3]);
          *(ushort4*)((u16*)out1 + ((size_t)(btq * 16 + hh) * 96 + dd) * 1152 + nn) = pk;
        }
      } else if (mode == 2) {
        float* O = (float*)out0;
#pragma unroll
        for (int r = 0; r < 4; ++r) O[(size_t)(row0 + r) * N + c] += acc[i][j][r];
      } else {
        u16* O = (u16*)out0;
#pragma unroll
        for (int r = 0; r < 4; ++r) {
          float v = acc[i][j][r];
          if (mode == 1) v = 0.5f * v * (1.f + erff(v * 0.70710678118f));
          O[(size_t)(row0 + r) * N + c] = f2bf(v);
        }
      }
    }
  }
}

// ---------------------------------------------------------------------------
// Flash attention. Block per (bt,h). 4 waves x 32 q-rows. Chunks of 128 kv;
// latent chunk (n=1024..1151, always unmasked) processed FIRST so the running
// max is finite before any possibly-masked media chunk (-1e30 bias -> P=0).
__global__ __launch_bounds__(256) void attn_kernel(const u16* __restrict__ Q,
                                                   const u16* __restrict__ Kb,
                                                   const u16* __restrict__ Vt,
                                                   const float* __restrict__ vmask,
                                                   u16* __restrict__ O) {
  const int bh = blockIdx.x;  // bt*16 + h
  const int bt = bh >> 4;
  const int h = bh & 15;
  const int bb = bt >> 2;  // batch index
  const int t = threadIdx.x, l = t & 63, w = t >> 6;
  const int lr = l & 15, lg = l >> 4;

  __shared__ float bias[1152];
  __shared__ u16 Plds[4][32 * 136];  // per-wave P scratch, padded stride

  for (int i = t; i < 1024; i += 256)
    bias[i] = (vmask[bb * 1024 + i] > 0.f) ? 0.f : -1e30f;
  if (t < 128) bias[1024 + t] = 0.f;
  __syncthreads();

  bf16x8 qf[2][3];
#pragma unroll
  for (int mt = 0; mt < 2; ++mt)
#pragma unroll
    for (int ks = 0; ks < 3; ++ks)
      qf[mt][ks] = *(const bf16x8*)(Q +
          (size_t)(bt * 128 + w * 32 + mt * 16 + lr) * 1536 + h * 96 + ks * 32 + lg * 8);

  f32x4 oa[2][6] = {};
  float m_i[2][4], l_i[2][4];
#pragma unroll
  for (int mt = 0; mt < 2; ++mt)
#pragma unroll
    for (int r = 0; r < 4; ++r) {
      m_i[mt][r] = -1e30f;
      l_i[mt][r] = 0.f;
    }

  const float L2E = 1.44269504088896f;
  u16* myP = &Plds[w][0];

  for (int ci = 0; ci < 9; ++ci) {
    const int chunk = (ci == 0) ? 8 : (ci - 1);
    const int nb = chunk * 128;

    // S = Q K^T + bias  (C-layout: col=kv idx, rows=q rows)
    f32x4 s[2][8];
#pragma unroll
    for (int nt = 0; nt < 8; ++nt) {
      f32x4 s0 = {}, s1 = {};
      const u16* kp =
          Kb + (size_t)(bt * 1152 + nb + nt * 16 + lr) * 1536 + h * 96 + lg * 8;
#pragma unroll
      for (int ks = 0; ks < 3; ++ks) {
        bf16x8 kf = *(const bf16x8*)(kp + ks * 32);
        s0 = MFMA16(qf[0][ks], kf, s0);
        s1 = MFMA16(qf[1][ks], kf, s1);
      }
      const float bn = bias[nb + nt * 16 + lr];
      s[0][nt] = s0 + bn;
      s[1][nt] = s1 + bn;
    }

    // online softmax update
    float alpha[2][4];
#pragma unroll
    for (int mt = 0; mt < 2; ++mt)
#pragma unroll
      for (int r = 0; r < 4; ++r) {
        float mx = s[mt][0][r];
#pragma unroll
        for (int nt = 1; nt < 8; ++nt) mx = fmaxf(mx, s[mt][nt][r]);
#pragma unroll
        for (int d = 1; d < 16; d <<= 1) mx = fmaxf(mx, __shfl_xor(mx, d));
        const float mn = fmaxf(m_i[mt][r], mx);
        alpha[mt][r] = exp2f((m_i[mt][r] - mn) * L2E);
        m_i[mt][r] = mn;
      }

#pragma unroll
    for (int mt = 0; mt < 2; ++mt) {
      float rsum[4] = {0.f, 0.f, 0.f, 0.f};
#pragma unroll
      for (int nt = 0; nt < 8; ++nt)
#pragma unroll
        for (int r = 0; r < 4; ++r) {
          const float pv = exp2f((s[mt][nt][r] - m_i[mt][r]) * L2E);
          rsum[r] += pv;
          myP[(mt * 16 + 4 * lg + r) * 136 + nt * 16 + lr] = f2bf(pv);
        }
#pragma unroll
      for (int r = 0; r < 4; ++r) {
        float rs = rsum[r];
#pragma unroll
        for (int d = 1; d < 16; d <<= 1) rs += __shfl_xor(rs, d);
        l_i[mt][r] = alpha[mt][r] * l_i[mt][r] + rs;
      }
    }

#pragma unroll
    for (int mt = 0; mt < 2; ++mt)
#pragma unroll
      for (int dt = 0; dt < 6; ++dt)
#pragma unroll
        for (int r = 0; r < 4; ++r) oa[mt][dt][r] *= alpha[mt][r];

    __syncthreads();  // P writes drained (lgkmcnt) before A-frag reads

    // O += P @ V   (A-frags from Plds, B-frags contiguous from transposed Vt)
#pragma unroll
    for (int dt = 0; dt < 6; ++dt) {
      const u16* vp = Vt + ((size_t)bh * 96 + dt * 16 + lr) * 1152 + nb + lg * 8;
#pragma unroll
      for (int ks = 0; ks < 4; ++ks) {
        bf16x8 vf = *(const bf16x8*)(vp + ks * 32);
        bf16x8 p0 = *(const bf16x8*)&myP[lr * 136 + ks * 32 + lg * 8];
        bf16x8 p1 = *(const bf16x8*)&myP[(16 + lr) * 136 + ks * 32 + lg * 8];
        oa[0][dt] = MFMA16(p0, vf, oa[0][dt]);
        oa[1][dt] = MFMA16(p1, vf, oa[1][dt]);
      }
    }
    __syncthreads();
  }

#pragma unroll
  for (int mt = 0; mt < 2; ++mt)
#pragma unroll
    for (int r = 0; r < 4; ++r) {
      const float inv = 1.f / l_i[mt][r];
#pragma unroll
      for (int dt = 0; dt < 6; ++dt)
        O[(size_t)(bt * 128 + w * 32 + mt * 16 + 4 * lg + r) * 1536 + h * 96 +
          dt * 16 + lr] = f2bf(oa[mt][dt][r] * inv);
    }
}

// ---------------------------------------------------------------------------
extern "C" void kernel_launch(void* const* d_in, const int* in_sizes, int n_in,
                              void* d_out, int out_size, void* d_ws, size_t ws_size,
                              hipStream_t stream) {
  const float* x = (const float*)d_in[0];
  const float* vmask = (const float*)d_in[1];
  const float* latents = (const float*)d_in[2];
  const float* ln_m_g = (const float*)d_in[3];
  const float* ln_m_b = (const float*)d_in[4];
  const float* ln_l_g = (const float*)d_in[5];
  const float* ln_l_b = (const float*)d_in[6];
  const float* q_w = (const float*)d_in[7];
  const float* kv_w = (const float*)d_in[8];
  const float* out_w = (const float*)d_in[9];
  const float* ff_ln_g = (const float*)d_in[10];
  const float* ff_ln_b = (const float*)d_in[11];
  const float* ff_w1 = (const float*)d_in[12];
  const float* ff_w2 = (const float*)d_in[13];
  const float* fn_g = (const float*)d_in[14];
  const float* fn_b = (const float*)d_in[15];

  char* p = (char*)d_ws;
  auto alloc = [&](size_t n) {
    char* r = p;
    p += (n + 255) & ~(size_t)255;
    return r;
  };
  u16* kvin = (u16*)alloc((size_t)36864 * 1024 * 2);   // [bt*1152+n][1024] bf16
  u16* lmq = (u16*)alloc((size_t)4096 * 1024 * 2);     // LN(lat) plain rows
  u16* qbuf = (u16*)alloc((size_t)4096 * 1536 * 2);    // scaled q
  u16* Kbuf = (u16*)alloc((size_t)36864 * 1536 * 2);   // K row-major
  u16* Vtb = (u16*)alloc((size_t)512 * 96 * 1152 * 2); // V transposed [bh][d][n]
  u16* obuf = (u16*)alloc((size_t)4096 * 1536 * 2);    // attn out
  u16* latln = (u16*)alloc((size_t)4096 * 1024 * 2);   // FF LN
  u16* ffh = (u16*)alloc((size_t)4096 * 4096 * 2);     // FF hidden
  float* lat = (float*)alloc((size_t)4096 * 1024 * 4); // running latents fp32
  u16* kvwT = (u16*)alloc((size_t)3072 * 1024 * 2);
  u16* qwT = (u16*)alloc((size_t)1536 * 1024 * 2);
  u16* outwT = (u16*)alloc((size_t)1024 * 1536 * 2);
  u16* ffw1T = (u16*)alloc((size_t)4096 * 1024 * 2);
  u16* ffw2T = (u16*)alloc((size_t)1024 * 4096 * 2);
  (void)in_sizes; (void)n_in; (void)out_size; (void)ws_size;

  init_lat<<<4096, 256, 0, stream>>>(latents, lat);

  const float qscale = 0.10206207261596577f;  // 96^-0.5, folded into q weights

  for (int L = 0; L < 6; ++L) {
    wcastT<<<dim3(96, 32), 256, 0, stream>>>(kv_w + (size_t)L * 1024 * 3072, kvwT, 1024, 3072, 1.f);
    wcastT<<<dim3(48, 32), 256, 0, stream>>>(q_w + (size_t)L * 1024 * 1536, qwT, 1024, 1536, qscale);
    wcastT<<<dim3(32, 48), 256, 0, stream>>>(out_w + (size_t)L * 1536 * 1024, outwT, 1536, 1024, 1.f);
    wcastT<<<dim3(128, 32), 256, 0, stream>>>(ff_w1 + (size_t)L * 1024 * 4096, ffw1T, 1024, 4096, 1.f);
    wcastT<<<dim3(32, 128), 256, 0, stream>>>(ff_w2 + (size_t)L * 4096 * 1024, ffw2T, 4096, 1024, 1.f);

    // LN(x) -> kvin media rows (bt*1152 + n)
    ln1024_bf16<<<32768, 256, 0, stream>>>(x, ln_m_g + L * 1024, ln_m_b + L * 1024,
                                           kvin, 1024, 1152, 0, nullptr);
    // LN(lat) -> kvin latent rows (bt*1152 + 1024 + i) and lmq plain
    ln1024_bf16<<<4096, 256, 0, stream>>>(lat, ln_l_g + L * 1024, ln_l_b + L * 1024,
                                          kvin, 128, 1152, 1024, lmq);

    // q = LN(lat) @ q_w * scale
    gemm_bt<<<dim3(12, 32), 256, 0, stream>>>(lmq, qwT, 4096, 1536, 1024, 0, qbuf, nullptr);
    // kv = [xm; lm] @ kv_w  -> K (row-major) + V (transposed)
    gemm_bt<<<dim3(24, 288), 256, 0, stream>>>(kvin, kvwT, 36864, 3072, 1024, 3, Kbuf, Vtb);
    // attention
    attn_kernel<<<512, 256, 0, stream>>>(qbuf, Kbuf, Vtb, vmask, obuf);
    // lat += o @ out_w
    gemm_bt<<<dim3(8, 32), 256, 0, stream>>>(obuf, outwT, 4096, 1024, 1536, 2, lat, nullptr);
    // FF: lat += gelu(LN(lat) @ w1) @ w2
    ln1024_bf16<<<4096, 256, 0, stream>>>(lat, ff_ln_g + L * 1024, ff_ln_b + L * 1024,
                                          latln, 4096, 0, 0, nullptr);
    gemm_bt<<<dim3(32, 32), 256, 0, stream>>>(latln, ffw1T, 4096, 4096, 1024, 1, ffh, nullptr);
    gemm_bt<<<dim3(8, 32), 256, 0, stream>>>(ffh, ffw2T, 4096, 1024, 4096, 2, lat, nullptr);
  }

  ln1024_f32<<<4096, 256, 0, stream>>>(lat, fn_g, fn_b, (float*)d_out);
}

// Round 2
// 5051.979 us; speedup vs baseline: 1.1593x; 1.1593x over previous
//
#include <hip/hip_runtime.h>

// PerceiverResampler on MI355X (gfx950), bf16 MFMA implementation.
// Round 2: mask-compacted media tokens (skip K/V of masked tokens), media LN
// hoisted out of the layer loop via g/b fold into weights + epilogue bias row,
// Q + latent-KV merged into one GEMM, split-K atomic epilogue for small-N GEMMs.

typedef __attribute__((ext_vector_type(8))) short bf16x8;
typedef __attribute__((ext_vector_type(4))) float f32x4;
typedef unsigned int u32;
typedef unsigned short u16;

#define MFMA16(a, b, c) __builtin_amdgcn_mfma_f32_16x16x32_bf16((a), (b), (c), 0, 0, 0)

__device__ __forceinline__ u16 f2bf(float f) {
  u32 u = __builtin_bit_cast(u32, f);
  u = (u + 0x7fffu + ((u >> 16) & 1u)) >> 16;  // RNE; inputs finite
  return (u16)u;
}

__device__ __forceinline__ void gld_lds16(const void* g, void* l) {
  __builtin_amdgcn_global_load_lds(
      (const __attribute__((address_space(1))) u32*)g,
      (__attribute__((address_space(3))) u32*)l, 16, 0, 0);
}

// ---------------------------------------------------------------------------
// mask scan: per batch b, compacted destination slot for each valid media token
__global__ __launch_bounds__(256) void maskscan(const float* __restrict__ vm,
                                                int* __restrict__ dest,
                                                int* __restrict__ cnt,
                                                int* __restrict__ cntp) {
  const int b = blockIdx.x, t = threadIdx.x;
  int v[4], s = 0;
#pragma unroll
  for (int i = 0; i < 4; ++i) {
    v[i] = vm[b * 1024 + t * 4 + i] > 0.f ? 1 : 0;
    s += v[i];
  }
  const int lane = t & 63, w = t >> 6;
  int ps = s;
#pragma unroll
  for (int d = 1; d < 64; d <<= 1) {
    int o = __shfl_up(ps, d);
    if (lane >= d) ps += o;
  }
  __shared__ int wsum[4];
  if (lane == 63) wsum[w] = ps;
  __syncthreads();
  int wb = 0;
  for (int i = 0; i < w; ++i) wb += wsum[i];
  int base = wb + ps - s;  // exclusive prefix
#pragma unroll
  for (int i = 0; i < 4; ++i) {
    dest[b * 1024 + t * 4 + i] = v[i] ? base : -1;
    base += v[i];
  }
  if (t == 255) {
    const int tot = wb + ps;
    cnt[b] = tot;
    cntp[b] = (tot + 127) & ~127;
  }
}

// build list of valid 128-row media tiles (row base in the bt*1152 space)
__global__ void tilebuild(const int* __restrict__ cntp, int* __restrict__ tileRows,
                          int* __restrict__ tileCnt) {
  if (threadIdx.x != 0 || blockIdx.x != 0) return;
  int n = 0;
  for (int bt = 0; bt < 32; ++bt) {
    const int nt = cntp[bt >> 2] >> 7;
    for (int j = 0; j < nt; ++j) tileRows[n++] = bt * 1152 + j * 128;
  }
  *tileCnt = n;
}

// ---------------------------------------------------------------------------
// init: lat[bt*128+i][:] = latents[i][:]
__global__ __launch_bounds__(256) void init_lat(const float* __restrict__ latents,
                                                float* __restrict__ lat) {
  const int r = blockIdx.x;  // 0..4095
  ((float4*)(lat + (size_t)r * 1024))[threadIdx.x] =
      ((const float4*)(latents + (size_t)(r & 127) * 1024))[threadIdx.x];
}

// ---------------------------------------------------------------------------
// transpose-cast: W (KxN fp32) -> WT (NxK bf16), optional scalar scale and
// optional per-k gain fold (gk may be null).
__global__ __launch_bounds__(256) void wcastT(const float* __restrict__ W,
                                              u16* __restrict__ WT, int K, int N,
                                              float scale,
                                              const float* __restrict__ gk) {
  __shared__ float tile[32][33];
  const int tx = threadIdx.x & 31;
  const int ty = threadIdx.x >> 5;  // 0..7
  const int n0 = blockIdx.x * 32;
  const int k0 = blockIdx.y * 32;
#pragma unroll
  for (int i = 0; i < 4; ++i) {
    const int kk = k0 + ty + i * 8;
    float w = W[(size_t)kk * N + n0 + tx];
    if (gk) w *= gk[kk];
    tile[ty + i * 8][tx] = w;
  }
  __syncthreads();
#pragma unroll
  for (int i = 0; i < 4; ++i)
    WT[(size_t)(n0 + ty + i * 8) * K + k0 + tx] = f2bf(tile[tx][ty + i * 8] * scale);
}

// bias row: r[n] = sum_k bvec[k] * W[k][n]   (N = 3072)
__global__ __launch_bounds__(256) void biasrow(const float* __restrict__ bvec,
                                               const float* __restrict__ W,
                                               float* __restrict__ r) {
  const int n = blockIdx.x * 256 + threadIdx.x;
  float acc = 0.f;
  for (int k = 0; k < 1024; ++k) acc += bvec[k] * W[(size_t)k * 3072 + n];
  r[n] = acc;
}

// ---------------------------------------------------------------------------
// LN0 (no gain/bias) of media rows of x, gathered into compacted kvin slots.
__global__ __launch_bounds__(256) void ln0_gather(const float* __restrict__ x,
                                                  const int* __restrict__ dest,
                                                  u16* __restrict__ kvin) {
  const int r = blockIdx.x;  // bt*1024 + tok
  const int bt = r >> 10, tok = r & 1023, b = bt >> 2;
  const int di = dest[b * 1024 + tok];
  if (di < 0) return;
  const int t = threadIdx.x;
  float4 xv = ((const float4*)(x + (size_t)r * 1024))[t];
  float s = xv.x + xv.y + xv.z + xv.w;
  float s2 = xv.x * xv.x + xv.y * xv.y + xv.z * xv.z + xv.w * xv.w;
#pragma unroll
  for (int d = 1; d < 64; d <<= 1) {
    s += __shfl_xor(s, d);
    s2 += __shfl_xor(s2, d);
  }
  __shared__ float red[8];
  const int w = t >> 6;
  if ((t & 63) == 0) {
    red[w] = s;
    red[4 + w] = s2;
  }
  __syncthreads();
  s = red[0] + red[1] + red[2] + red[3];
  s2 = red[4] + red[5] + red[6] + red[7];
  const float mu = s * (1.f / 1024.f);
  const float rs = rsqrtf(fmaxf(s2 * (1.f / 1024.f) - mu * mu, 0.f) + 1e-5f);
  ushort4 o;
  o.x = f2bf((xv.x - mu) * rs);
  o.y = f2bf((xv.y - mu) * rs);
  o.z = f2bf((xv.z - mu) * rs);
  o.w = f2bf((xv.w - mu) * rs);
  ((ushort4*)(kvin + ((size_t)bt * 1152 + di) * 1024))[t] = o;
}

// ---------------------------------------------------------------------------
// LayerNorm of a 1024-wide row -> bf16, with output row remap:
//   orow = (r/grp)*stride + off + (r%grp);  optional second plain-row output.
__global__ __launch_bounds__(256) void ln1024_bf16(
    const float* __restrict__ in, const float* __restrict__ g,
    const float* __restrict__ b, u16* __restrict__ out1, int grp, int stride,
    int off, u16* __restrict__ out2) {
  const int r = blockIdx.x;
  const int t = threadIdx.x;
  float4 xv = ((const float4*)(in + (size_t)r * 1024))[t];
  float s = xv.x + xv.y + xv.z + xv.w;
  float s2 = xv.x * xv.x + xv.y * xv.y + xv.z * xv.z + xv.w * xv.w;
#pragma unroll
  for (int d = 1; d < 64; d <<= 1) {
    s += __shfl_xor(s, d);
    s2 += __shfl_xor(s2, d);
  }
  __shared__ float red[8];
  const int w = t >> 6;
  if ((t & 63) == 0) {
    red[w] = s;
    red[4 + w] = s2;
  }
  __syncthreads();
  s = red[0] + red[1] + red[2] + red[3];
  s2 = red[4] + red[5] + red[6] + red[7];
  const float mu = s * (1.f / 1024.f);
  const float rs = rsqrtf(fmaxf(s2 * (1.f / 1024.f) - mu * mu, 0.f) + 1e-5f);
  float4 gv = ((const float4*)g)[t];
  float4 bv = ((const float4*)b)[t];
  ushort4 o;
  o.x = f2bf((xv.x - mu) * rs * gv.x + bv.x);
  o.y = f2bf((xv.y - mu) * rs * gv.y + bv.y);
  o.z = f2bf((xv.z - mu) * rs * gv.z + bv.z);
  o.w = f2bf((xv.w - mu) * rs * gv.w + bv.w);
  const size_t orow = (size_t)(r / grp) * stride + off + (r % grp);
  ((ushort4*)(out1 + orow * 1024))[t] = o;
  if (out2) ((ushort4*)(out2 + (size_t)r * 1024))[t] = o;
}

// final LN -> fp32 out
__global__ __launch_bounds__(256) void ln1024_f32(const float* __restrict__ in,
                                                  const float* __restrict__ g,
                                                  const float* __restrict__ b,
                                                  float* __restrict__ out) {
  const int r = blockIdx.x;
  const int t = threadIdx.x;
  float4 xv = ((const float4*)(in + (size_t)r * 1024))[t];
  float s = xv.x + xv.y + xv.z + xv.w;
  float s2 = xv.x * xv.x + xv.y * xv.y + xv.z * xv.z + xv.w * xv.w;
#pragma unroll
  for (int d = 1; d < 64; d <<= 1) {
    s += __shfl_xor(s, d);
    s2 += __shfl_xor(s2, d);
  }
  __shared__ float red[8];
  const int w = t >> 6;
  if ((t & 63) == 0) {
    red[w] = s;
    red[4 + w] = s2;
  }
  __syncthreads();
  s = red[0] + red[1] + red[2] + red[3];
  s2 = red[4] + red[5] + red[6] + red[7];
  const float mu = s * (1.f / 1024.f);
  const float rs = rsqrtf(fmaxf(s2 * (1.f / 1024.f) - mu * mu, 0.f) + 1e-5f);
  float4 gv = ((const float4*)g)[t];
  float4 bv = ((const float4*)b)[t];
  float4 o;
  o.x = (xv.x - mu) * rs * gv.x + bv.x;
  o.y = (xv.y - mu) * rs * gv.y + bv.y;
  o.z = (xv.z - mu) * rs * gv.z + bv.z;
  o.w = (xv.w - mu) * rs * gv.w + bv.w;
  ((float4*)(out + (size_t)r * 1024))[t] = o;
}

// ---------------------------------------------------------------------------
// GEMM: C(128x128 tile) = A(MxK bf16) @ BT(NxK bf16)^T, BK=32, fp32 acc.
// m0 from tileRows[] if given (media-compacted tiles), else blockIdx.y*128.
// K range [z*Ksplit, (z+1)*Ksplit) for split-K launches.
// mode 1: gelu(exact) -> bf16 (ldc=N)
// mode 2: fp32 atomicAdd into out0 (residual, split-K safe)
// mode 3: media KV: +rbias[c]; c<1536 -> K rows (out0, ld 1536);
//         else V -> out1 transposed [bt*16+h][d][n]
// mode 4: latent QKV: c<1536 -> q (out0, ld 1536); c<3072 -> K latent rows
//         (out1); else V latent cols -> out2 transposed
__global__ __launch_bounds__(256) void gemm_bt(
    const u16* __restrict__ A, const u16* __restrict__ BT, int N, int K, int mode,
    void* __restrict__ out0, void* __restrict__ out1, void* __restrict__ out2,
    const float* __restrict__ rbias, const int* __restrict__ tileRows,
    const int* __restrict__ tileCnt, int Ksplit) {
  int m0;
  if (tileRows) {
    if ((int)blockIdx.y >= *tileCnt) return;
    m0 = tileRows[blockIdx.y];
  } else {
    m0 = blockIdx.y * 128;
  }
  __shared__ u16 Alds[128 * 32];
  __shared__ u16 Blds[128 * 32];
  const int t = threadIdx.x;
  const int l = t & 63;
  const int w = t >> 6;
  const int n0 = blockIdx.x * 128;
  const int wr = (w >> 1) * 64;
  const int wc = (w & 1) * 64;
  const int arow = t >> 2;       // staging row (per round)
  const int acol = (t & 3) * 8;  // staging k offset
  const int frow = l & 15;       // fragment row within 16
  const int fk = (l >> 4) * 8;   // fragment k offset

  f32x4 acc[4][4] = {};

  const u16* Ap = A + (size_t)(m0 + arow) * K + acol;
  const u16* Ap2 = A + (size_t)(m0 + 64 + arow) * K + acol;
  const u16* Bp = BT + (size_t)(n0 + arow) * K + acol;
  const u16* Bp2 = BT + (size_t)(n0 + 64 + arow) * K + acol;

  const int koff = blockIdx.z * Ksplit;
  for (int k0 = koff; k0 < koff + Ksplit; k0 += 32) {
    __syncthreads();
    gld_lds16(Ap + k0, &Alds[t * 8]);
    gld_lds16(Ap2 + k0, &Alds[2048 + t * 8]);
    gld_lds16(Bp + k0, &Blds[t * 8]);
    gld_lds16(Bp2 + k0, &Blds[2048 + t * 8]);
    __syncthreads();
    bf16x8 af[4], bfr[4];
#pragma unroll
    for (int i = 0; i < 4; ++i)
      af[i] = *(const bf16x8*)&Alds[(wr + i * 16 + frow) * 32 + fk];
#pragma unroll
    for (int j = 0; j < 4; ++j)
      bfr[j] = *(const bf16x8*)&Blds[(wc + j * 16 + frow) * 32 + fk];
#pragma unroll
    for (int i = 0; i < 4; ++i)
#pragma unroll
      for (int j = 0; j < 4; ++j) acc[i][j] = MFMA16(af[i], bfr[j], acc[i][j]);
  }

  const int col = l & 15;
  const int r4 = (l >> 4) * 4;
  const int btq = m0 / 1152;        // media tile: owning bt (mode 3)
  const int nbase = m0 - btq * 1152;
#pragma unroll
  for (int i = 0; i < 4; ++i) {
    const int roff = wr + i * 16 + r4;  // row within tile
    const int row0 = m0 + roff;
#pragma unroll
    for (int j = 0; j < 4; ++j) {
      const int c = n0 + wc + j * 16 + col;
      if (mode == 3) {
        const float bc = rbias[c];
        if (c < 1536) {
          u16* Kb = (u16*)out0;
#pragma unroll
          for (int r = 0; r < 4; ++r)
            Kb[(size_t)(row0 + r) * 1536 + c] = f2bf(acc[i][j][r] + bc);
        } else {
          const int cc = c - 1536;
          const int hh = cc / 96, dd = cc - hh * 96;
          ushort4 pk;
          pk.x = f2bf(acc[i][j][0] + bc);
          pk.y = f2bf(acc[i][j][1] + bc);
          pk.z = f2bf(acc[i][j][2] + bc);
          pk.w = f2bf(acc[i][j][3] + bc);
          *(ushort4*)((u16*)out1 +
                      ((size_t)(btq * 16 + hh) * 96 + dd) * 1152 + nbase + roff) = pk;
        }
      } else if (mode == 4) {
        const int bt = row0 >> 7, ii = row0 & 127;
        if (c < 1536) {
          u16* Qb = (u16*)out0;
#pragma unroll
          for (int r = 0; r < 4; ++r)
            Qb[(size_t)(row0 + r) * 1536 + c] = f2bf(acc[i][j][r]);
        } else if (c < 3072) {
          u16* Kb = (u16*)out1;
#pragma unroll
          for (int r = 0; r < 4; ++r)
            Kb[((size_t)bt * 1152 + 1024 + ii + r) * 1536 + (c - 1536)] =
                f2bf(acc[i][j][r]);
        } else {
          const int cc = c - 3072;
          const int hh = cc / 96, dd = cc - hh * 96;
          ushort4 pk;
          pk.x = f2bf(acc[i][j][0]);
          pk.y = f2bf(acc[i][j][1]);
          pk.z = f2bf(acc[i][j][2]);
          pk.w = f2bf(acc[i][j][3]);
          *(ushort4*)((u16*)out2 +
                      ((size_t)(bt * 16 + hh) * 96 + dd) * 1152 + 1024 + ii) = pk;
        }
      } else if (mode == 2) {
        float* O = (float*)out0;
#pragma unroll
        for (int r = 0; r < 4; ++r)
          atomicAdd(&O[(size_t)(row0 + r) * N + c], acc[i][j][r]);
      } else {
        u16* O = (u16*)out0;
#pragma unroll
        for (int r = 0; r < 4; ++r) {
          float v = acc[i][j][r];
          if (mode == 1) v = 0.5f * v * (1.f + erff(v * 0.70710678118f));
          O[(size_t)(row0 + r) * N + c] = f2bf(v);
        }
      }
    }
  }
}

// ---------------------------------------------------------------------------
// Flash attention over compacted KV. Block per (bt,h). 4 waves x 32 q-rows.
// Chunk 0 = latents (rows 1024..1151, always valid); then media chunks up to
// cnt_pad; compacted media slot n valid iff n < cnt (else bias -1e30).
__global__ __launch_bounds__(256) void attn_kernel(
    const u16* __restrict__ Q, const u16* __restrict__ Kb,
    const u16* __restrict__ Vt, const int* __restrict__ cnt_d,
    const int* __restrict__ cntp_d, u16* __restrict__ O) {
  const int bh = blockIdx.x;  // bt*16 + h
  const int bt = bh >> 4;
  const int h = bh & 15;
  const int bb = bt >> 2;  // batch index
  const int t = threadIdx.x, l = t & 63, w = t >> 6;
  const int lr = l & 15, lg = l >> 4;

  const int cnt = cnt_d[bb];
  const int nchunks = 1 + (cntp_d[bb] >> 7);

  __shared__ u16 Plds[4][32 * 136];  // per-wave P scratch, padded stride

  bf16x8 qf[2][3];
#pragma unroll
  for (int mt = 0; mt < 2; ++mt)
#pragma unroll
    for (int ks = 0; ks < 3; ++ks)
      qf[mt][ks] = *(const bf16x8*)(Q +
          (size_t)(bt * 128 + w * 32 + mt * 16 + lr) * 1536 + h * 96 + ks * 32 + lg * 8);

  f32x4 oa[2][6] = {};
  float m_i[2][4], l_i[2][4];
#pragma unroll
  for (int mt = 0; mt < 2; ++mt)
#pragma unroll
    for (int r = 0; r < 4; ++r) {
      m_i[mt][r] = -1e30f;
      l_i[mt][r] = 0.f;
    }

  const float L2E = 1.44269504088896f;
  u16* myP = &Plds[w][0];

  for (int ci = 0; ci < nchunks; ++ci) {
    const int nb = (ci == 0) ? 1024 : (ci - 1) * 128;

    // S = Q K^T + bias  (C-layout: col=kv idx, rows=q rows)
    f32x4 s[2][8];
#pragma unroll
    for (int nt = 0; nt < 8; ++nt) {
      f32x4 s0 = {}, s1 = {};
      const u16* kp =
          Kb + (size_t)(bt * 1152 + nb + nt * 16 + lr) * 1536 + h * 96 + lg * 8;
#pragma unroll
      for (int ks = 0; ks < 3; ++ks) {
        bf16x8 kf = *(const bf16x8*)(kp + ks * 32);
        s0 = MFMA16(qf[0][ks], kf, s0);
        s1 = MFMA16(qf[1][ks], kf, s1);
      }
      const float bn =
          (nb >= 1024) ? 0.f : (((nb + nt * 16 + lr) < cnt) ? 0.f : -1e30f);
      s[0][nt] = s0 + bn;
      s[1][nt] = s1 + bn;
    }

    // online softmax update
    float alpha[2][4];
#pragma unroll
    for (int mt = 0; mt < 2; ++mt)
#pragma unroll
      for (int r = 0; r < 4; ++r) {
        float mx = s[mt][0][r];
#pragma unroll
        for (int nt = 1; nt < 8; ++nt) mx = fmaxf(mx, s[mt][nt][r]);
#pragma unroll
        for (int d = 1; d < 16; d <<= 1) mx = fmaxf(mx, __shfl_xor(mx, d));
        const float mn = fmaxf(m_i[mt][r], mx);
        alpha[mt][r] = exp2f((m_i[mt][r] - mn) * L2E);
        m_i[mt][r] = mn;
      }

#pragma unroll
    for (int mt = 0; mt < 2; ++mt) {
      float rsum[4] = {0.f, 0.f, 0.f, 0.f};
#pragma unroll
      for (int nt = 0; nt < 8; ++nt)
#pragma unroll
        for (int r = 0; r < 4; ++r) {
          const float pv = exp2f((s[mt][nt][r] - m_i[mt][r]) * L2E);
          rsum[r] += pv;
          myP[(mt * 16 + 4 * lg + r) * 136 + nt * 16 + lr] = f2bf(pv);
        }
#pragma unroll
      for (int r = 0; r < 4; ++r) {
        float rs = rsum[r];
#pragma unroll
        for (int d = 1; d < 16; d <<= 1) rs += __shfl_xor(rs, d);
        l_i[mt][r] = alpha[mt][r] * l_i[mt][r] + rs;
      }
    }

#pragma unroll
    for (int mt = 0; mt < 2; ++mt)
#pragma unroll
      for (int dt = 0; dt < 6; ++dt)
#pragma unroll
        for (int r = 0; r < 4; ++r) oa[mt][dt][r] *= alpha[mt][r];

    __syncthreads();  // P writes drained before A-frag reads

    // O += P @ V   (A-frags from Plds, B-frags contiguous from transposed Vt)
#pragma unroll
    for (int dt = 0; dt < 6; ++dt) {
      const u16* vp = Vt + ((size_t)bh * 96 + dt * 16 + lr) * 1152 + nb + lg * 8;
#pragma unroll
      for (int ks = 0; ks < 4; ++ks) {
        bf16x8 vf = *(const bf16x8*)(vp + ks * 32);
        bf16x8 p0 = *(const bf16x8*)&myP[lr * 136 + ks * 32 + lg * 8];
        bf16x8 p1 = *(const bf16x8*)&myP[(16 + lr) * 136 + ks * 32 + lg * 8];
        oa[0][dt] = MFMA16(p0, vf, oa[0][dt]);
        oa[1][dt] = MFMA16(p1, vf, oa[1][dt]);
      }
    }
    __syncthreads();
  }

#pragma unroll
  for (int mt = 0; mt < 2; ++mt)
#pragma unroll
    for (int r = 0; r < 4; ++r) {
      const float inv = 1.f / l_i[mt][r];
#pragma unroll
      for (int dt = 0; dt < 6; ++dt)
        O[(size_t)(bt * 128 + w * 32 + mt * 16 + 4 * lg + r) * 1536 + h * 96 +
          dt * 16 + lr] = f2bf(oa[mt][dt][r] * inv);
    }
}

// ---------------------------------------------------------------------------
extern "C" void kernel_launch(void* const* d_in, const int* in_sizes, int n_in,
                              void* d_out, int out_size, void* d_ws, size_t ws_size,
                              hipStream_t stream) {
  const float* x = (const float*)d_in[0];
  const float* vmask = (const float*)d_in[1];
  const float* latents = (const float*)d_in[2];
  const float* ln_m_g = (const float*)d_in[3];
  const float* ln_m_b = (const float*)d_in[4];
  const float* ln_l_g = (const float*)d_in[5];
  const float* ln_l_b = (const float*)d_in[6];
  const float* q_w = (const float*)d_in[7];
  const float* kv_w = (const float*)d_in[8];
  const float* out_w = (const float*)d_in[9];
  const float* ff_ln_g = (const float*)d_in[10];
  const float* ff_ln_b = (const float*)d_in[11];
  const float* ff_w1 = (const float*)d_in[12];
  const float* ff_w2 = (const float*)d_in[13];
  const float* fn_g = (const float*)d_in[14];
  const float* fn_b = (const float*)d_in[15];

  char* p = (char*)d_ws;
  auto alloc = [&](size_t n) {
    char* r = p;
    p += (n + 255) & ~(size_t)255;
    return r;
  };
  u16* kvin = (u16*)alloc((size_t)36864 * 1024 * 2);   // compact LN0(x) + lm rows
  u16* lmq = (u16*)alloc((size_t)4096 * 1024 * 2);     // LN(lat) plain rows
  u16* qbuf = (u16*)alloc((size_t)4096 * 1536 * 2);    // scaled q
  u16* Kbuf = (u16*)alloc((size_t)36864 * 1536 * 2);   // K row-major (1152/bt)
  u16* Vtb = (u16*)alloc((size_t)512 * 96 * 1152 * 2); // V transposed [bh][d][n]
  u16* obuf = (u16*)alloc((size_t)4096 * 1536 * 2);    // attn out
  float* lat = (float*)alloc((size_t)4096 * 1024 * 4); // running latents fp32
  u16* kvwTm = (u16*)alloc((size_t)3072 * 1024 * 2);   // kv_w folded w/ ln_m_g
  u16* qkvT = (u16*)alloc((size_t)4608 * 1024 * 2);    // [q_w*scale ; kv_w] NxK
  u16* outwT = (u16*)alloc((size_t)1024 * 1536 * 2);
  u16* ffw1T = (u16*)alloc((size_t)4096 * 1024 * 2);
  u16* ffw2T = (u16*)alloc((size_t)1024 * 4096 * 2);
  float* rbias = (float*)alloc(3072 * 4);
  int* dest = (int*)alloc(8192 * 4);
  int* cntd = (int*)alloc(64);
  int* cntp = (int*)alloc(64);
  int* tileRows = (int*)alloc(260 * 4);
  int* tileCnt = (int*)alloc(4);
  u16* latln = lmq;          // alias: lmq dead by FF-LN time
  u16* ffh = Kbuf;           // alias: Kbuf dead after attention
  (void)in_sizes; (void)n_in; (void)out_size; (void)ws_size;

  maskscan<<<8, 256, 0, stream>>>(vmask, dest, cntd, cntp);
  tilebuild<<<1, 1, 0, stream>>>(cntp, tileRows, tileCnt);
  ln0_gather<<<32768, 256, 0, stream>>>(x, dest, kvin);
  init_lat<<<4096, 256, 0, stream>>>(latents, lat);

  const float qscale = 0.10206207261596577f;  // 96^-0.5, folded into q weights

  for (int L = 0; L < 6; ++L) {
    // weight casts (bf16, NxK) + media bias row
    wcastT<<<dim3(96, 32), 256, 0, stream>>>(kv_w + (size_t)L * 1024 * 3072, kvwTm,
                                             1024, 3072, 1.f, ln_m_g + L * 1024);
    biasrow<<<12, 256, 0, stream>>>(ln_m_b + L * 1024, kv_w + (size_t)L * 1024 * 3072,
                                    rbias);
    wcastT<<<dim3(48, 32), 256, 0, stream>>>(q_w + (size_t)L * 1024 * 1536, qkvT,
                                             1024, 1536, qscale, nullptr);
    wcastT<<<dim3(96, 32), 256, 0, stream>>>(kv_w + (size_t)L * 1024 * 3072,
                                             qkvT + (size_t)1536 * 1024, 1024, 3072,
                                             1.f, nullptr);
    wcastT<<<dim3(32, 48), 256, 0, stream>>>(out_w + (size_t)L * 1536 * 1024, outwT,
                                             1536, 1024, 1.f, nullptr);
    wcastT<<<dim3(128, 32), 256, 0, stream>>>(ff_w1 + (size_t)L * 1024 * 4096, ffw1T,
                                              1024, 4096, 1.f, nullptr);
    wcastT<<<dim3(32, 128), 256, 0, stream>>>(ff_w2 + (size_t)L * 4096 * 1024, ffw2T,
                                              4096, 1024, 1.f, nullptr);

    // LN(lat) -> kvin latent rows (bt*1152+1024+i) and lmq plain
    ln1024_bf16<<<4096, 256, 0, stream>>>(lat, ln_l_g + L * 1024, ln_l_b + L * 1024,
                                          kvin, 128, 1152, 1024, lmq);

    // media KV over valid tiles only: K/V = LN0x @ (g.kv_w) + b@kv_w
    gemm_bt<<<dim3(24, 256), 256, 0, stream>>>(kvin, kvwTm, 3072, 1024, 3, Kbuf, Vtb,
                                               nullptr, rbias, tileRows, tileCnt, 1024);
    // latent Q/K/V: lm @ [q_w*s ; kv_w]
    gemm_bt<<<dim3(36, 32), 256, 0, stream>>>(lmq, qkvT, 4608, 1024, 4, qbuf, Kbuf,
                                              Vtb, nullptr, nullptr, nullptr, 1024);
    // attention
    attn_kernel<<<512, 256, 0, stream>>>(qbuf, Kbuf, Vtb, cntd, cntp, obuf);
    // lat += o @ out_w  (split-K x4, atomic)
    gemm_bt<<<dim3(8, 32, 4), 256, 0, stream>>>(obuf, outwT, 1024, 1536, 2, lat,
                                                nullptr, nullptr, nullptr, nullptr,
                                                nullptr, 384);
    // FF: lat += gelu(LN(lat) @ w1) @ w2
    ln1024_bf16<<<4096, 256, 0, stream>>>(lat, ff_ln_g + L * 1024, ff_ln_b + L * 1024,
                                          latln, 4096, 0, 0, nullptr);
    gemm_bt<<<dim3(32, 32), 256, 0, stream>>>(latln, ffw1T, 4096, 1024, 1, ffh,
                                              nullptr, nullptr, nullptr, nullptr,
                                              nullptr, 1024);
    gemm_bt<<<dim3(8, 32, 4), 256, 0, stream>>>(ffh, ffw2T, 1024, 4096, 2, lat,
                                                nullptr, nullptr, nullptr, nullptr,
                                                nullptr, 1024);
  }

  ln1024_f32<<<4096, 256, 0, stream>>>(lat, fn_g, fn_b, (float*)d_out);
}

// Round 3
// 4513.922 us; speedup vs baseline: 1.2975x; 1.1192x over previous
//
#include <hip/hip_runtime.h>

// PerceiverResampler on MI355X (gfx950), bf16 MFMA implementation.
// Round 3: atomic split-K replaced by fp32 partials + fused reduce+LayerNorm
// kernels; GEMM K-loop widened to BK=64 (two 128x32 panels, 32 MFMA/barrier);
// biasrow parallelized. Mask compaction + LN-fold from round 2 retained.

typedef __attribute__((ext_vector_type(8))) short bf16x8;
typedef __attribute__((ext_vector_type(4))) float f32x4;
typedef unsigned int u32;
typedef unsigned short u16;

#define MFMA16(a, b, c) __builtin_amdgcn_mfma_f32_16x16x32_bf16((a), (b), (c), 0, 0, 0)

__device__ __forceinline__ u16 f2bf(float f) {
  u32 u = __builtin_bit_cast(u32, f);
  u = (u + 0x7fffu + ((u >> 16) & 1u)) >> 16;  // RNE; inputs finite
  return (u16)u;
}

__device__ __forceinline__ void gld_lds16(const void* g, void* l) {
  __builtin_amdgcn_global_load_lds(
      (const __attribute__((address_space(1))) u32*)g,
      (__attribute__((address_space(3))) u32*)l, 16, 0, 0);
}

// ---------------------------------------------------------------------------
// mask scan: per batch b, compacted destination slot for each valid media token
__global__ __launch_bounds__(256) void maskscan(const float* __restrict__ vm,
                                                int* __restrict__ dest,
                                                int* __restrict__ cnt,
                                                int* __restrict__ cntp) {
  const int b = blockIdx.x, t = threadIdx.x;
  int v[4], s = 0;
#pragma unroll
  for (int i = 0; i < 4; ++i) {
    v[i] = vm[b * 1024 + t * 4 + i] > 0.f ? 1 : 0;
    s += v[i];
  }
  const int lane = t & 63, w = t >> 6;
  int ps = s;
#pragma unroll
  for (int d = 1; d < 64; d <<= 1) {
    int o = __shfl_up(ps, d);
    if (lane >= d) ps += o;
  }
  __shared__ int wsum[4];
  if (lane == 63) wsum[w] = ps;
  __syncthreads();
  int wb = 0;
  for (int i = 0; i < w; ++i) wb += wsum[i];
  int base = wb + ps - s;  // exclusive prefix
#pragma unroll
  for (int i = 0; i < 4; ++i) {
    dest[b * 1024 + t * 4 + i] = v[i] ? base : -1;
    base += v[i];
  }
  if (t == 255) {
    const int tot = wb + ps;
    cnt[b] = tot;
    cntp[b] = (tot + 127) & ~127;
  }
}

// build list of valid 128-row media tiles (row base in the bt*1152 space)
__global__ void tilebuild(const int* __restrict__ cntp, int* __restrict__ tileRows,
                          int* __restrict__ tileCnt) {
  if (threadIdx.x != 0 || blockIdx.x != 0) return;
  int n = 0;
  for (int bt = 0; bt < 32; ++bt) {
    const int nt = cntp[bt >> 2] >> 7;
    for (int j = 0; j < nt; ++j) tileRows[n++] = bt * 1152 + j * 128;
  }
  *tileCnt = n;
}

// ---------------------------------------------------------------------------
// init: lat[bt*128+i][:] = latents[i][:]
__global__ __launch_bounds__(256) void init_lat(const float* __restrict__ latents,
                                                float* __restrict__ lat) {
  const int r = blockIdx.x;  // 0..4095
  ((float4*)(lat + (size_t)r * 1024))[threadIdx.x] =
      ((const float4*)(latents + (size_t)(r & 127) * 1024))[threadIdx.x];
}

// ---------------------------------------------------------------------------
// transpose-cast: W (KxN fp32) -> WT (NxK bf16), optional scalar scale and
// optional per-k gain fold (gk may be null).
__global__ __launch_bounds__(256) void wcastT(const float* __restrict__ W,
                                              u16* __restrict__ WT, int K, int N,
                                              float scale,
                                              const float* __restrict__ gk) {
  __shared__ float tile[32][33];
  const int tx = threadIdx.x & 31;
  const int ty = threadIdx.x >> 5;  // 0..7
  const int n0 = blockIdx.x * 32;
  const int k0 = blockIdx.y * 32;
#pragma unroll
  for (int i = 0; i < 4; ++i) {
    const int kk = k0 + ty + i * 8;
    float w = W[(size_t)kk * N + n0 + tx];
    if (gk) w *= gk[kk];
    tile[ty + i * 8][tx] = w;
  }
  __syncthreads();
#pragma unroll
  for (int i = 0; i < 4; ++i)
    WT[(size_t)(n0 + ty + i * 8) * K + k0 + tx] = f2bf(tile[tx][ty + i * 8] * scale);
}

// rbias zero + chunked accumulation: r[n] = sum_k bvec[k] * W[k][n]  (N=3072)
__global__ __launch_bounds__(256) void zero3072(float* __restrict__ r) {
  r[blockIdx.x * 256 + threadIdx.x] = 0.f;
}
__global__ __launch_bounds__(256) void biasrow2(const float* __restrict__ bvec,
                                                const float* __restrict__ W,
                                                float* __restrict__ r) {
  const int n = blockIdx.x * 256 + threadIdx.x;
  const int k0 = blockIdx.y * 64;
  float acc = 0.f;
#pragma unroll 8
  for (int k = 0; k < 64; ++k) acc += bvec[k0 + k] * W[(size_t)(k0 + k) * 3072 + n];
  atomicAdd(&r[n], acc);
}

// ---------------------------------------------------------------------------
// LN0 (no gain/bias) of media rows of x, gathered into compacted kvin slots.
__global__ __launch_bounds__(256) void ln0_gather(const float* __restrict__ x,
                                                  const int* __restrict__ dest,
                                                  u16* __restrict__ kvin) {
  const int r = blockIdx.x;  // bt*1024 + tok
  const int bt = r >> 10, tok = r & 1023, b = bt >> 2;
  const int di = dest[b * 1024 + tok];
  if (di < 0) return;
  const int t = threadIdx.x;
  float4 xv = ((const float4*)(x + (size_t)r * 1024))[t];
  float s = xv.x + xv.y + xv.z + xv.w;
  float s2 = xv.x * xv.x + xv.y * xv.y + xv.z * xv.z + xv.w * xv.w;
#pragma unroll
  for (int d = 1; d < 64; d <<= 1) {
    s += __shfl_xor(s, d);
    s2 += __shfl_xor(s2, d);
  }
  __shared__ float red[8];
  const int w = t >> 6;
  if ((t & 63) == 0) {
    red[w] = s;
    red[4 + w] = s2;
  }
  __syncthreads();
  s = red[0] + red[1] + red[2] + red[3];
  s2 = red[4] + red[5] + red[6] + red[7];
  const float mu = s * (1.f / 1024.f);
  const float rs = rsqrtf(fmaxf(s2 * (1.f / 1024.f) - mu * mu, 0.f) + 1e-5f);
  ushort4 o;
  o.x = f2bf((xv.x - mu) * rs);
  o.y = f2bf((xv.y - mu) * rs);
  o.z = f2bf((xv.z - mu) * rs);
  o.w = f2bf((xv.w - mu) * rs);
  ((ushort4*)(kvin + ((size_t)bt * 1152 + di) * 1024))[t] = o;
}

// ---------------------------------------------------------------------------
// LayerNorm of a 1024-wide row -> bf16, with output row remap:
//   orow = (r/grp)*stride + off + (r%grp);  optional second plain-row output.
__global__ __launch_bounds__(256) void ln1024_bf16(
    const float* __restrict__ in, const float* __restrict__ g,
    const float* __restrict__ b, u16* __restrict__ out1, int grp, int stride,
    int off, u16* __restrict__ out2) {
  const int r = blockIdx.x;
  const int t = threadIdx.x;
  float4 xv = ((const float4*)(in + (size_t)r * 1024))[t];
  float s = xv.x + xv.y + xv.z + xv.w;
  float s2 = xv.x * xv.x + xv.y * xv.y + xv.z * xv.z + xv.w * xv.w;
#pragma unroll
  for (int d = 1; d < 64; d <<= 1) {
    s += __shfl_xor(s, d);
    s2 += __shfl_xor(s2, d);
  }
  __shared__ float red[8];
  const int w = t >> 6;
  if ((t & 63) == 0) {
    red[w] = s;
    red[4 + w] = s2;
  }
  __syncthreads();
  s = red[0] + red[1] + red[2] + red[3];
  s2 = red[4] + red[5] + red[6] + red[7];
  const float mu = s * (1.f / 1024.f);
  const float rs = rsqrtf(fmaxf(s2 * (1.f / 1024.f) - mu * mu, 0.f) + 1e-5f);
  float4 gv = ((const float4*)g)[t];
  float4 bv = ((const float4*)b)[t];
  ushort4 o;
  o.x = f2bf((xv.x - mu) * rs * gv.x + bv.x);
  o.y = f2bf((xv.y - mu) * rs * gv.y + bv.y);
  o.z = f2bf((xv.z - mu) * rs * gv.z + bv.z);
  o.w = f2bf((xv.w - mu) * rs * gv.w + bv.w);
  const size_t orow = (size_t)(r / grp) * stride + off + (r % grp);
  ((ushort4*)(out1 + orow * 1024))[t] = o;
  if (out2) ((ushort4*)(out2 + (size_t)r * 1024))[t] = o;
}

// ---------------------------------------------------------------------------
// Fused: lat[r] += sum_z part[z][r]; then LN(lat[r]) -> bf16 out1 (row remap)
// / bf16 out2 (plain) / fp32 outf (plain). Replaces atomic split-K epilogues.
__global__ __launch_bounds__(256) void red4_ln(
    const float* __restrict__ part, float* __restrict__ lat,
    const float* __restrict__ g, const float* __restrict__ b,
    u16* __restrict__ out1, int grp, int stride, int off,
    u16* __restrict__ out2, float* __restrict__ outf) {
  const int r = blockIdx.x;
  const int t = threadIdx.x;
  float4 xv = ((const float4*)(lat + (size_t)r * 1024))[t];
#pragma unroll
  for (int z = 0; z < 4; ++z) {
    float4 pz = ((const float4*)(part + (size_t)z * 4194304 + (size_t)r * 1024))[t];
    xv.x += pz.x; xv.y += pz.y; xv.z += pz.z; xv.w += pz.w;
  }
  ((float4*)(lat + (size_t)r * 1024))[t] = xv;
  float s = xv.x + xv.y + xv.z + xv.w;
  float s2 = xv.x * xv.x + xv.y * xv.y + xv.z * xv.z + xv.w * xv.w;
#pragma unroll
  for (int d = 1; d < 64; d <<= 1) {
    s += __shfl_xor(s, d);
    s2 += __shfl_xor(s2, d);
  }
  __shared__ float red[8];
  const int w = t >> 6;
  if ((t & 63) == 0) {
    red[w] = s;
    red[4 + w] = s2;
  }
  __syncthreads();
  s = red[0] + red[1] + red[2] + red[3];
  s2 = red[4] + red[5] + red[6] + red[7];
  const float mu = s * (1.f / 1024.f);
  const float rs = rsqrtf(fmaxf(s2 * (1.f / 1024.f) - mu * mu, 0.f) + 1e-5f);
  float4 gv = ((const float4*)g)[t];
  float4 bv = ((const float4*)b)[t];
  float4 o;
  o.x = (xv.x - mu) * rs * gv.x + bv.x;
  o.y = (xv.y - mu) * rs * gv.y + bv.y;
  o.z = (xv.z - mu) * rs * gv.z + bv.z;
  o.w = (xv.w - mu) * rs * gv.w + bv.w;
  if (out1) {
    ushort4 ob;
    ob.x = f2bf(o.x); ob.y = f2bf(o.y); ob.z = f2bf(o.z); ob.w = f2bf(o.w);
    const size_t orow = (size_t)(r / grp) * stride + off + (r % grp);
    ((ushort4*)(out1 + orow * 1024))[t] = ob;
    if (out2) ((ushort4*)(out2 + (size_t)r * 1024))[t] = ob;
  }
  if (outf) ((float4*)(outf + (size_t)r * 1024))[t] = o;
}

// ---------------------------------------------------------------------------
// GEMM: C(128x128 tile) = A(MxK bf16) @ BT(NxK bf16)^T, BK=64 (two 128x32
// panels -> 32 MFMA per barrier), fp32 acc.
// m0 from tileRows[] if given (media-compacted tiles), else blockIdx.y*128.
// K range [z*Ksplit, (z+1)*Ksplit) for split-K launches.
// mode 1: gelu(exact) -> bf16 (ldc=N)
// mode 3: media KV: +rbias[c]; c<1536 -> K rows (out0, ld 1536);
//         else V -> out1 transposed [bt*16+h][d][n]
// mode 4: latent QKV: c<1536 -> q (out0, ld 1536); c<3072 -> K latent rows
//         (out1); else V latent cols -> out2 transposed
// mode 5: fp32 partial store to out0 + z*4096*1024 (ldc=N)
__global__ __launch_bounds__(256) void gemm_bt(
    const u16* __restrict__ A, const u16* __restrict__ BT, int N, int K, int mode,
    void* __restrict__ out0, void* __restrict__ out1, void* __restrict__ out2,
    const float* __restrict__ rbias, const int* __restrict__ tileRows,
    const int* __restrict__ tileCnt, int Ksplit) {
  int m0;
  if (tileRows) {
    if ((int)blockIdx.y >= *tileCnt) return;
    m0 = tileRows[blockIdx.y];
  } else {
    m0 = blockIdx.y * 128;
  }
  __shared__ u16 Alds[2 * 128 * 32];  // [panel][row][32]
  __shared__ u16 Blds[2 * 128 * 32];
  const int t = threadIdx.x;
  const int l = t & 63;
  const int w = t >> 6;
  const int n0 = blockIdx.x * 128;
  const int wr = (w >> 1) * 64;
  const int wc = (w & 1) * 64;
  const int srow = t >> 2;       // staging row (per round)
  const int scol = (t & 3) * 8;  // staging k offset
  const int frow = l & 15;       // fragment row within 16
  const int fk = (l >> 4) * 8;   // fragment k offset

  f32x4 acc[4][4] = {};

  const u16* Ab = A + (size_t)(m0 + srow) * K + scol;
  const u16* Bb = BT + (size_t)(n0 + srow) * K + scol;
  const size_t r64K = (size_t)64 * K;

  const int koff = blockIdx.z * Ksplit;
  for (int k0 = koff; k0 < koff + Ksplit; k0 += 64) {
    __syncthreads();
    gld_lds16(Ab + k0, &Alds[t * 8]);                    // panel0 rows 0..63
    gld_lds16(Ab + r64K + k0, &Alds[2048 + t * 8]);      // panel0 rows 64..127
    gld_lds16(Ab + k0 + 32, &Alds[4096 + t * 8]);        // panel1 rows 0..63
    gld_lds16(Ab + r64K + k0 + 32, &Alds[6144 + t * 8]); // panel1 rows 64..127
    gld_lds16(Bb + k0, &Blds[t * 8]);
    gld_lds16(Bb + r64K + k0, &Blds[2048 + t * 8]);
    gld_lds16(Bb + k0 + 32, &Blds[4096 + t * 8]);
    gld_lds16(Bb + r64K + k0 + 32, &Blds[6144 + t * 8]);
    __syncthreads();
#pragma unroll
    for (int ph = 0; ph < 2; ++ph) {
      bf16x8 af[4], bfr[4];
#pragma unroll
      for (int i = 0; i < 4; ++i)
        af[i] = *(const bf16x8*)&Alds[ph * 4096 + (wr + i * 16 + frow) * 32 + fk];
#pragma unroll
      for (int j = 0; j < 4; ++j)
        bfr[j] = *(const bf16x8*)&Blds[ph * 4096 + (wc + j * 16 + frow) * 32 + fk];
#pragma unroll
      for (int i = 0; i < 4; ++i)
#pragma unroll
        for (int j = 0; j < 4; ++j) acc[i][j] = MFMA16(af[i], bfr[j], acc[i][j]);
    }
  }

  const int col = l & 15;
  const int r4 = (l >> 4) * 4;
  const int btq = m0 / 1152;  // media tile: owning bt (mode 3)
  const int nbase = m0 - btq * 1152;
#pragma unroll
  for (int i = 0; i < 4; ++i) {
    const int roff = wr + i * 16 + r4;  // row within tile
    const int row0 = m0 + roff;
#pragma unroll
    for (int j = 0; j < 4; ++j) {
      const int c = n0 + wc + j * 16 + col;
      if (mode == 3) {
        const float bc = rbias[c];
        if (c < 1536) {
          u16* Kb = (u16*)out0;
#pragma unroll
          for (int r = 0; r < 4; ++r)
            Kb[(size_t)(row0 + r) * 1536 + c] = f2bf(acc[i][j][r] + bc);
        } else {
          const int cc = c - 1536;
          const int hh = cc / 96, dd = cc - hh * 96;
          ushort4 pk;
          pk.x = f2bf(acc[i][j][0] + bc);
          pk.y = f2bf(acc[i][j][1] + bc);
          pk.z = f2bf(acc[i][j][2] + bc);
          pk.w = f2bf(acc[i][j][3] + bc);
          *(ushort4*)((u16*)out1 +
                      ((size_t)(btq * 16 + hh) * 96 + dd) * 1152 + nbase + roff) = pk;
        }
      } else if (mode == 4) {
        const int bt = row0 >> 7, ii = row0 & 127;
        if (c < 1536) {
          u16* Qb = (u16*)out0;
#pragma unroll
          for (int r = 0; r < 4; ++r)
            Qb[(size_t)(row0 + r) * 1536 + c] = f2bf(acc[i][j][r]);
        } else if (c < 3072) {
          u16* Kb = (u16*)out1;
#pragma unroll
          for (int r = 0; r < 4; ++r)
            Kb[((size_t)bt * 1152 + 1024 + ii + r) * 1536 + (c - 1536)] =
                f2bf(acc[i][j][r]);
        } else {
          const int cc = c - 3072;
          const int hh = cc / 96, dd = cc - hh * 96;
          ushort4 pk;
          pk.x = f2bf(acc[i][j][0]);
          pk.y = f2bf(acc[i][j][1]);
          pk.z = f2bf(acc[i][j][2]);
          pk.w = f2bf(acc[i][j][3]);
          *(ushort4*)((u16*)out2 +
                      ((size_t)(bt * 16 + hh) * 96 + dd) * 1152 + 1024 + ii) = pk;
        }
      } else if (mode == 5) {
        float* O = (float*)out0 + (size_t)blockIdx.z * 4194304;
#pragma unroll
        for (int r = 0; r < 4; ++r) O[(size_t)(row0 + r) * N + c] = acc[i][j][r];
      } else {
        u16* O = (u16*)out0;
#pragma unroll
        for (int r = 0; r < 4; ++r) {
          float v = acc[i][j][r];
          if (mode == 1) v = 0.5f * v * (1.f + erff(v * 0.70710678118f));
          O[(size_t)(row0 + r) * N + c] = f2bf(v);
        }
      }
    }
  }
}

// ---------------------------------------------------------------------------
// Flash attention over compacted KV. Block per (bt,h). 4 waves x 32 q-rows.
// Chunk 0 = latents (rows 1024..1151, always valid); then media chunks up to
// cnt_pad; compacted media slot n valid iff n < cnt (else bias -1e30).
__global__ __launch_bounds__(256) void attn_kernel(
    const u16* __restrict__ Q, const u16* __restrict__ Kb,
    const u16* __restrict__ Vt, const int* __restrict__ cnt_d,
    const int* __restrict__ cntp_d, u16* __restrict__ O) {
  const int bh = blockIdx.x;  // bt*16 + h
  const int bt = bh >> 4;
  const int h = bh & 15;
  const int bb = bt >> 2;  // batch index
  const int t = threadIdx.x, l = t & 63, w = t >> 6;
  const int lr = l & 15, lg = l >> 4;

  const int cnt = cnt_d[bb];
  const int nchunks = 1 + (cntp_d[bb] >> 7);

  __shared__ u16 Plds[4][32 * 136];  // per-wave P scratch, padded stride

  bf16x8 qf[2][3];
#pragma unroll
  for (int mt = 0; mt < 2; ++mt)
#pragma unroll
    for (int ks = 0; ks < 3; ++ks)
      qf[mt][ks] = *(const bf16x8*)(Q +
          (size_t)(bt * 128 + w * 32 + mt * 16 + lr) * 1536 + h * 96 + ks * 32 + lg * 8);

  f32x4 oa[2][6] = {};
  float m_i[2][4], l_i[2][4];
#pragma unroll
  for (int mt = 0; mt < 2; ++mt)
#pragma unroll
    for (int r = 0; r < 4; ++r) {
      m_i[mt][r] = -1e30f;
      l_i[mt][r] = 0.f;
    }

  const float L2E = 1.44269504088896f;
  u16* myP = &Plds[w][0];

  for (int ci = 0; ci < nchunks; ++ci) {
    const int nb = (ci == 0) ? 1024 : (ci - 1) * 128;

    // S = Q K^T + bias  (C-layout: col=kv idx, rows=q rows)
    f32x4 s[2][8];
#pragma unroll
    for (int nt = 0; nt < 8; ++nt) {
      f32x4 s0 = {}, s1 = {};
      const u16* kp =
          Kb + (size_t)(bt * 1152 + nb + nt * 16 + lr) * 1536 + h * 96 + lg * 8;
#pragma unroll
      for (int ks = 0; ks < 3; ++ks) {
        bf16x8 kf = *(const bf16x8*)(kp + ks * 32);
        s0 = MFMA16(qf[0][ks], kf, s0);
        s1 = MFMA16(qf[1][ks], kf, s1);
      }
      const float bn =
          (nb >= 1024) ? 0.f : (((nb + nt * 16 + lr) < cnt) ? 0.f : -1e30f);
      s[0][nt] = s0 + bn;
      s[1][nt] = s1 + bn;
    }

    // online softmax update
    float alpha[2][4];
#pragma unroll
    for (int mt = 0; mt < 2; ++mt)
#pragma unroll
      for (int r = 0; r < 4; ++r) {
        float mx = s[mt][0][r];
#pragma unroll
        for (int nt = 1; nt < 8; ++nt) mx = fmaxf(mx, s[mt][nt][r]);
#pragma unroll
        for (int d = 1; d < 16; d <<= 1) mx = fmaxf(mx, __shfl_xor(mx, d));
        const float mn = fmaxf(m_i[mt][r], mx);
        alpha[mt][r] = exp2f((m_i[mt][r] - mn) * L2E);
        m_i[mt][r] = mn;
      }

#pragma unroll
    for (int mt = 0; mt < 2; ++mt) {
      float rsum[4] = {0.f, 0.f, 0.f, 0.f};
#pragma unroll
      for (int nt = 0; nt < 8; ++nt)
#pragma unroll
        for (int r = 0; r < 4; ++r) {
          const float pv = exp2f((s[mt][nt][r] - m_i[mt][r]) * L2E);
          rsum[r] += pv;
          myP[(mt * 16 + 4 * lg + r) * 136 + nt * 16 + lr] = f2bf(pv);
        }
#pragma unroll
      for (int r = 0; r < 4; ++r) {
        float rs = rsum[r];
#pragma unroll
        for (int d = 1; d < 16; d <<= 1) rs += __shfl_xor(rs, d);
        l_i[mt][r] = alpha[mt][r] * l_i[mt][r] + rs;
      }
    }

#pragma unroll
    for (int mt = 0; mt < 2; ++mt)
#pragma unroll
      for (int dt = 0; dt < 6; ++dt)
#pragma unroll
        for (int r = 0; r < 4; ++r) oa[mt][dt][r] *= alpha[mt][r];

    __syncthreads();  // P writes drained before A-frag reads

    // O += P @ V   (A-frags from Plds, B-frags contiguous from transposed Vt)
#pragma unroll
    for (int dt = 0; dt < 6; ++dt) {
      const u16* vp = Vt + ((size_t)bh * 96 + dt * 16 + lr) * 1152 + nb + lg * 8;
#pragma unroll
      for (int ks = 0; ks < 4; ++ks) {
        bf16x8 vf = *(const bf16x8*)(vp + ks * 32);
        bf16x8 p0 = *(const bf16x8*)&myP[lr * 136 + ks * 32 + lg * 8];
        bf16x8 p1 = *(const bf16x8*)&myP[(16 + lr) * 136 + ks * 32 + lg * 8];
        oa[0][dt] = MFMA16(p0, vf, oa[0][dt]);
        oa[1][dt] = MFMA16(p1, vf, oa[1][dt]);
      }
    }
    __syncthreads();
  }

#pragma unroll
  for (int mt = 0; mt < 2; ++mt)
#pragma unroll
    for (int r = 0; r < 4; ++r) {
      const float inv = 1.f / l_i[mt][r];
#pragma unroll
      for (int dt = 0; dt < 6; ++dt)
        O[(size_t)(bt * 128 + w * 32 + mt * 16 + 4 * lg + r) * 1536 + h * 96 +
          dt * 16 + lr] = f2bf(oa[mt][dt][r] * inv);
    }
}

// ---------------------------------------------------------------------------
extern "C" void kernel_launch(void* const* d_in, const int* in_sizes, int n_in,
                              void* d_out, int out_size, void* d_ws, size_t ws_size,
                              hipStream_t stream) {
  const float* x = (const float*)d_in[0];
  const float* vmask = (const float*)d_in[1];
  const float* latents = (const float*)d_in[2];
  const float* ln_m_g = (const float*)d_in[3];
  const float* ln_m_b = (const float*)d_in[4];
  const float* ln_l_g = (const float*)d_in[5];
  const float* ln_l_b = (const float*)d_in[6];
  const float* q_w = (const float*)d_in[7];
  const float* kv_w = (const float*)d_in[8];
  const float* out_w = (const float*)d_in[9];
  const float* ff_ln_g = (const float*)d_in[10];
  const float* ff_ln_b = (const float*)d_in[11];
  const float* ff_w1 = (const float*)d_in[12];
  const float* ff_w2 = (const float*)d_in[13];
  const float* fn_g = (const float*)d_in[14];
  const float* fn_b = (const float*)d_in[15];

  char* p = (char*)d_ws;
  auto alloc = [&](size_t n) {
    char* r = p;
    p += (n + 255) & ~(size_t)255;
    return r;
  };
  u16* kvin = (u16*)alloc((size_t)36864 * 1024 * 2);   // compact LN0(x) + lm rows
  u16* lmq = (u16*)alloc((size_t)4096 * 1024 * 2);     // LN(lat) plain rows
  u16* qbuf = (u16*)alloc((size_t)4096 * 1536 * 2);    // scaled q
  u16* Kbuf = (u16*)alloc((size_t)36864 * 1536 * 2);   // K row-major (1152/bt)
  u16* Vtb = (u16*)alloc((size_t)512 * 96 * 1152 * 2); // V transposed [bh][d][n]
  u16* obuf = (u16*)alloc((size_t)4096 * 1536 * 2);    // attn out
  float* lat = (float*)alloc((size_t)4096 * 1024 * 4); // running latents fp32
  u16* kvwTm = (u16*)alloc((size_t)3072 * 1024 * 2);   // kv_w folded w/ ln_m_g
  u16* qkvT = (u16*)alloc((size_t)4608 * 1024 * 2);    // [q_w*scale ; kv_w] NxK
  u16* outwT = (u16*)alloc((size_t)1024 * 1536 * 2);
  u16* ffw1T = (u16*)alloc((size_t)4096 * 1024 * 2);
  u16* ffw2T = (u16*)alloc((size_t)1024 * 4096 * 2);
  float* rbias = (float*)alloc(3072 * 4);
  int* dest = (int*)alloc(8192 * 4);
  int* cntd = (int*)alloc(64);
  int* cntp = (int*)alloc(64);
  int* tileRows = (int*)alloc(260 * 4);
  int* tileCnt = (int*)alloc(4);
  u16* latln = lmq;           // alias: lmq dead by FF-LN time
  u16* ffh = Vtb;             // alias: Vtb dead after attention (33.5MB <= 113MB)
  float* part = (float*)Kbuf; // alias: Kbuf dead after attention (67MB <= 113MB)
  (void)in_sizes; (void)n_in; (void)out_size; (void)ws_size;

  maskscan<<<8, 256, 0, stream>>>(vmask, dest, cntd, cntp);
  tilebuild<<<1, 1, 0, stream>>>(cntp, tileRows, tileCnt);
  ln0_gather<<<32768, 256, 0, stream>>>(x, dest, kvin);
  init_lat<<<4096, 256, 0, stream>>>(latents, lat);
  // layer-0 latent LN -> kvin latent rows + lmq
  ln1024_bf16<<<4096, 256, 0, stream>>>(lat, ln_l_g, ln_l_b, kvin, 128, 1152, 1024, lmq);

  const float qscale = 0.10206207261596577f;  // 96^-0.5, folded into q weights

  for (int L = 0; L < 6; ++L) {
    // weight casts (bf16, NxK) + media bias row
    wcastT<<<dim3(96, 32), 256, 0, stream>>>(kv_w + (size_t)L * 1024 * 3072, kvwTm,
                                             1024, 3072, 1.f, ln_m_g + L * 1024);
    zero3072<<<12, 256, 0, stream>>>(rbias);
    biasrow2<<<dim3(12, 16), 256, 0, stream>>>(ln_m_b + L * 1024,
                                               kv_w + (size_t)L * 1024 * 3072, rbias);
    wcastT<<<dim3(48, 32), 256, 0, stream>>>(q_w + (size_t)L * 1024 * 1536, qkvT,
                                             1024, 1536, qscale, nullptr);
    wcastT<<<dim3(96, 32), 256, 0, stream>>>(kv_w + (size_t)L * 1024 * 3072,
                                             qkvT + (size_t)1536 * 1024, 1024, 3072,
                                             1.f, nullptr);
    wcastT<<<dim3(32, 48), 256, 0, stream>>>(out_w + (size_t)L * 1536 * 1024, outwT,
                                             1536, 1024, 1.f, nullptr);
    wcastT<<<dim3(128, 32), 256, 0, stream>>>(ff_w1 + (size_t)L * 1024 * 4096, ffw1T,
                                              1024, 4096, 1.f, nullptr);
    wcastT<<<dim3(32, 128), 256, 0, stream>>>(ff_w2 + (size_t)L * 4096 * 1024, ffw2T,
                                              4096, 1024, 1.f, nullptr);

    // media KV over valid tiles only: K/V = LN0x @ (g.kv_w) + b@kv_w
    gemm_bt<<<dim3(24, 256), 256, 0, stream>>>(kvin, kvwTm, 3072, 1024, 3, Kbuf, Vtb,
                                               nullptr, rbias, tileRows, tileCnt, 1024);
    // latent Q/K/V: lm @ [q_w*s ; kv_w]
    gemm_bt<<<dim3(36, 32), 256, 0, stream>>>(lmq, qkvT, 4608, 1024, 4, qbuf, Kbuf,
                                              Vtb, nullptr, nullptr, nullptr, 1024);
    // attention
    attn_kernel<<<512, 256, 0, stream>>>(qbuf, Kbuf, Vtb, cntd, cntp, obuf);
    // o @ out_w -> fp32 partials (split-K x4); then lat += sum, FF-LN -> latln
    gemm_bt<<<dim3(8, 32, 4), 256, 0, stream>>>(obuf, outwT, 1024, 1536, 5, part,
                                                nullptr, nullptr, nullptr, nullptr,
                                                nullptr, 384);
    red4_ln<<<4096, 256, 0, stream>>>(part, lat, ff_ln_g + L * 1024,
                                      ff_ln_b + L * 1024, latln, 4096, 0, 0,
                                      nullptr, nullptr);
    // FF: hidden = gelu(latln @ w1); partials = hidden @ w2
    gemm_bt<<<dim3(32, 32), 256, 0, stream>>>(latln, ffw1T, 4096, 1024, 1, ffh,
                                              nullptr, nullptr, nullptr, nullptr,
                                              nullptr, 1024);
    gemm_bt<<<dim3(8, 32, 4), 256, 0, stream>>>(ffh, ffw2T, 1024, 4096, 5, part,
                                                nullptr, nullptr, nullptr, nullptr,
                                                nullptr, 1024);
    if (L < 5) {
      // lat += sum; next layer's latent LN -> kvin latent rows + lmq
      red4_ln<<<4096, 256, 0, stream>>>(part, lat, ln_l_g + (L + 1) * 1024,
                                        ln_l_b + (L + 1) * 1024, kvin, 128, 1152,
                                        1024, lmq, nullptr);
    } else {
      // lat += sum; final LN -> fp32 d_out
      red4_ln<<<4096, 256, 0, stream>>>(part, lat, fn_g, fn_b, nullptr, 1, 0, 0,
                                        nullptr, (float*)d_out);
    }
  }
}

// Round 4
// 3767.738 us; speedup vs baseline: 1.5545x; 1.1980x over previous
//
#include <hip/hip_runtime.h>

// PerceiverResampler on MI355X (gfx950), bf16 MFMA implementation.
// Round 4: BK reverted to 32 (BK=64 cost a block/CU of occupancy); GEMM
// templated on MODE + __launch_bounds__(256,4) to fit 128 regs -> 4 blocks/CU;
// four K=1024 weight casts fused into one launch. Round-2/3 structure kept.

typedef __attribute__((ext_vector_type(8))) short bf16x8;
typedef __attribute__((ext_vector_type(4))) float f32x4;
typedef unsigned int u32;
typedef unsigned short u16;

#define MFMA16(a, b, c) __builtin_amdgcn_mfma_f32_16x16x32_bf16((a), (b), (c), 0, 0, 0)

__device__ __forceinline__ u16 f2bf(float f) {
  u32 u = __builtin_bit_cast(u32, f);
  u = (u + 0x7fffu + ((u >> 16) & 1u)) >> 16;  // RNE; inputs finite
  return (u16)u;
}

__device__ __forceinline__ void gld_lds16(const void* g, void* l) {
  __builtin_amdgcn_global_load_lds(
      (const __attribute__((address_space(1))) u32*)g,
      (__attribute__((address_space(3))) u32*)l, 16, 0, 0);
}

// ---------------------------------------------------------------------------
// mask scan: per batch b, compacted destination slot for each valid media token
__global__ __launch_bounds__(256) void maskscan(const float* __restrict__ vm,
                                                int* __restrict__ dest,
                                                int* __restrict__ cnt,
                                                int* __restrict__ cntp) {
  const int b = blockIdx.x, t = threadIdx.x;
  int v[4], s = 0;
#pragma unroll
  for (int i = 0; i < 4; ++i) {
    v[i] = vm[b * 1024 + t * 4 + i] > 0.f ? 1 : 0;
    s += v[i];
  }
  const int lane = t & 63, w = t >> 6;
  int ps = s;
#pragma unroll
  for (int d = 1; d < 64; d <<= 1) {
    int o = __shfl_up(ps, d);
    if (lane >= d) ps += o;
  }
  __shared__ int wsum[4];
  if (lane == 63) wsum[w] = ps;
  __syncthreads();
  int wb = 0;
  for (int i = 0; i < w; ++i) wb += wsum[i];
  int base = wb + ps - s;  // exclusive prefix
#pragma unroll
  for (int i = 0; i < 4; ++i) {
    dest[b * 1024 + t * 4 + i] = v[i] ? base : -1;
    base += v[i];
  }
  if (t == 255) {
    const int tot = wb + ps;
    cnt[b] = tot;
    cntp[b] = (tot + 127) & ~127;
  }
}

// build list of valid 128-row media tiles (row base in the bt*1152 space)
__global__ void tilebuild(const int* __restrict__ cntp, int* __restrict__ tileRows,
                          int* __restrict__ tileCnt) {
  if (threadIdx.x != 0 || blockIdx.x != 0) return;
  int n = 0;
  for (int bt = 0; bt < 32; ++bt) {
    const int nt = cntp[bt >> 2] >> 7;
    for (int j = 0; j < nt; ++j) tileRows[n++] = bt * 1152 + j * 128;
  }
  *tileCnt = n;
}

// ---------------------------------------------------------------------------
// init: lat[bt*128+i][:] = latents[i][:]
__global__ __launch_bounds__(256) void init_lat(const float* __restrict__ latents,
                                                float* __restrict__ lat) {
  const int r = blockIdx.x;  // 0..4095
  ((float4*)(lat + (size_t)r * 1024))[threadIdx.x] =
      ((const float4*)(latents + (size_t)(r & 127) * 1024))[threadIdx.x];
}

// ---------------------------------------------------------------------------
// transpose-cast: W (KxN fp32) -> WT (NxK bf16), optional scalar scale and
// optional per-k gain fold (gk may be null).
__global__ __launch_bounds__(256) void wcastT(const float* __restrict__ W,
                                              u16* __restrict__ WT, int K, int N,
                                              float scale,
                                              const float* __restrict__ gk) {
  __shared__ float tile[32][33];
  const int tx = threadIdx.x & 31;
  const int ty = threadIdx.x >> 5;  // 0..7
  const int n0 = blockIdx.x * 32;
  const int k0 = blockIdx.y * 32;
#pragma unroll
  for (int i = 0; i < 4; ++i) {
    const int kk = k0 + ty + i * 8;
    float w = W[(size_t)kk * N + n0 + tx];
    if (gk) w *= gk[kk];
    tile[ty + i * 8][tx] = w;
  }
  __syncthreads();
#pragma unroll
  for (int i = 0; i < 4; ++i)
    WT[(size_t)(n0 + ty + i * 8) * K + k0 + tx] = f2bf(tile[tx][ty + i * 8] * scale);
}

// fused transpose-cast of the four K=1024 weights for one layer:
//   nt 0..95   : kvwTm = kv_w * ln_m_g     (N=3072)
//   nt 96..143 : qkvT[0:1536]   = q_w * qscale
//   nt 144..239: qkvT[1536:4608]= kv_w
//   nt 240..367: ffw1T = ff_w1             (N=4096)
__global__ __launch_bounds__(256) void wcast4(const float* __restrict__ kv_w,
                                              const float* __restrict__ q_w,
                                              const float* __restrict__ ff_w1,
                                              const float* __restrict__ g,
                                              float qscale, u16* __restrict__ kvwTm,
                                              u16* __restrict__ qkvT,
                                              u16* __restrict__ ffw1T) {
  const int nt = blockIdx.x;
  const float* W;
  u16* D;
  int N, n0;
  const float* gk = nullptr;
  float sc = 1.f;
  if (nt < 96) {
    W = kv_w; D = kvwTm; N = 3072; n0 = nt * 32; gk = g;
  } else if (nt < 144) {
    W = q_w; D = qkvT; N = 1536; n0 = (nt - 96) * 32; sc = qscale;
  } else if (nt < 240) {
    W = kv_w; D = qkvT + (size_t)1536 * 1024; N = 3072; n0 = (nt - 144) * 32;
  } else {
    W = ff_w1; D = ffw1T; N = 4096; n0 = (nt - 240) * 32;
  }
  __shared__ float tile[32][33];
  const int tx = threadIdx.x & 31;
  const int ty = threadIdx.x >> 5;
  const int k0 = blockIdx.y * 32;
#pragma unroll
  for (int i = 0; i < 4; ++i) {
    const int kk = k0 + ty + i * 8;
    float w = W[(size_t)kk * N + n0 + tx];
    if (gk) w *= gk[kk];
    tile[ty + i * 8][tx] = w;
  }
  __syncthreads();
#pragma unroll
  for (int i = 0; i < 4; ++i)
    D[(size_t)(n0 + ty + i * 8) * 1024 + k0 + tx] = f2bf(tile[tx][ty + i * 8] * sc);
}

// rbias zero + chunked accumulation: r[n] = sum_k bvec[k] * W[k][n]  (N=3072)
__global__ __launch_bounds__(256) void zero3072(float* __restrict__ r) {
  r[blockIdx.x * 256 + threadIdx.x] = 0.f;
}
__global__ __launch_bounds__(256) void biasrow2(const float* __restrict__ bvec,
                                                const float* __restrict__ W,
                                                float* __restrict__ r) {
  const int n = blockIdx.x * 256 + threadIdx.x;
  const int k0 = blockIdx.y * 64;
  float acc = 0.f;
#pragma unroll 8
  for (int k = 0; k < 64; ++k) acc += bvec[k0 + k] * W[(size_t)(k0 + k) * 3072 + n];
  atomicAdd(&r[n], acc);
}

// ---------------------------------------------------------------------------
// LN0 (no gain/bias) of media rows of x, gathered into compacted kvin slots.
__global__ __launch_bounds__(256) void ln0_gather(const float* __restrict__ x,
                                                  const int* __restrict__ dest,
                                                  u16* __restrict__ kvin) {
  const int r = blockIdx.x;  // bt*1024 + tok
  const int bt = r >> 10, tok = r & 1023, b = bt >> 2;
  const int di = dest[b * 1024 + tok];
  if (di < 0) return;
  const int t = threadIdx.x;
  float4 xv = ((const float4*)(x + (size_t)r * 1024))[t];
  float s = xv.x + xv.y + xv.z + xv.w;
  float s2 = xv.x * xv.x + xv.y * xv.y + xv.z * xv.z + xv.w * xv.w;
#pragma unroll
  for (int d = 1; d < 64; d <<= 1) {
    s += __shfl_xor(s, d);
    s2 += __shfl_xor(s2, d);
  }
  __shared__ float red[8];
  const int w = t >> 6;
  if ((t & 63) == 0) {
    red[w] = s;
    red[4 + w] = s2;
  }
  __syncthreads();
  s = red[0] + red[1] + red[2] + red[3];
  s2 = red[4] + red[5] + red[6] + red[7];
  const float mu = s * (1.f / 1024.f);
  const float rs = rsqrtf(fmaxf(s2 * (1.f / 1024.f) - mu * mu, 0.f) + 1e-5f);
  ushort4 o;
  o.x = f2bf((xv.x - mu) * rs);
  o.y = f2bf((xv.y - mu) * rs);
  o.z = f2bf((xv.z - mu) * rs);
  o.w = f2bf((xv.w - mu) * rs);
  ((ushort4*)(kvin + ((size_t)bt * 1152 + di) * 1024))[t] = o;
}

// ---------------------------------------------------------------------------
// LayerNorm of a 1024-wide row -> bf16, with output row remap:
//   orow = (r/grp)*stride + off + (r%grp);  optional second plain-row output.
__global__ __launch_bounds__(256) void ln1024_bf16(
    const float* __restrict__ in, const float* __restrict__ g,
    const float* __restrict__ b, u16* __restrict__ out1, int grp, int stride,
    int off, u16* __restrict__ out2) {
  const int r = blockIdx.x;
  const int t = threadIdx.x;
  float4 xv = ((const float4*)(in + (size_t)r * 1024))[t];
  float s = xv.x + xv.y + xv.z + xv.w;
  float s2 = xv.x * xv.x + xv.y * xv.y + xv.z * xv.z + xv.w * xv.w;
#pragma unroll
  for (int d = 1; d < 64; d <<= 1) {
    s += __shfl_xor(s, d);
    s2 += __shfl_xor(s2, d);
  }
  __shared__ float red[8];
  const int w = t >> 6;
  if ((t & 63) == 0) {
    red[w] = s;
    red[4 + w] = s2;
  }
  __syncthreads();
  s = red[0] + red[1] + red[2] + red[3];
  s2 = red[4] + red[5] + red[6] + red[7];
  const float mu = s * (1.f / 1024.f);
  const float rs = rsqrtf(fmaxf(s2 * (1.f / 1024.f) - mu * mu, 0.f) + 1e-5f);
  float4 gv = ((const float4*)g)[t];
  float4 bv = ((const float4*)b)[t];
  ushort4 o;
  o.x = f2bf((xv.x - mu) * rs * gv.x + bv.x);
  o.y = f2bf((xv.y - mu) * rs * gv.y + bv.y);
  o.z = f2bf((xv.z - mu) * rs * gv.z + bv.z);
  o.w = f2bf((xv.w - mu) * rs * gv.w + bv.w);
  const size_t orow = (size_t)(r / grp) * stride + off + (r % grp);
  ((ushort4*)(out1 + orow * 1024))[t] = o;
  if (out2) ((ushort4*)(out2 + (size_t)r * 1024))[t] = o;
}

// ---------------------------------------------------------------------------
// Fused: lat[r] += sum_z part[z][r]; then LN(lat[r]) -> bf16 out1 (row remap)
// / bf16 out2 (plain) / fp32 outf (plain). Replaces atomic split-K epilogues.
__global__ __launch_bounds__(256) void red4_ln(
    const float* __restrict__ part, float* __restrict__ lat,
    const float* __restrict__ g, const float* __restrict__ b,
    u16* __restrict__ out1, int grp, int stride, int off,
    u16* __restrict__ out2, float* __restrict__ outf) {
  const int r = blockIdx.x;
  const int t = threadIdx.x;
  float4 xv = ((const float4*)(lat + (size_t)r * 1024))[t];
#pragma unroll
  for (int z = 0; z < 4; ++z) {
    float4 pz = ((const float4*)(part + (size_t)z * 4194304 + (size_t)r * 1024))[t];
    xv.x += pz.x; xv.y += pz.y; xv.z += pz.z; xv.w += pz.w;
  }
  ((float4*)(lat + (size_t)r * 1024))[t] = xv;
  float s = xv.x + xv.y + xv.z + xv.w;
  float s2 = xv.x * xv.x + xv.y * xv.y + xv.z * xv.z + xv.w * xv.w;
#pragma unroll
  for (int d = 1; d < 64; d <<= 1) {
    s += __shfl_xor(s, d);
    s2 += __shfl_xor(s2, d);
  }
  __shared__ float red[8];
  const int w = t >> 6;
  if ((t & 63) == 0) {
    red[w] = s;
    red[4 + w] = s2;
  }
  __syncthreads();
  s = red[0] + red[1] + red[2] + red[3];
  s2 = red[4] + red[5] + red[6] + red[7];
  const float mu = s * (1.f / 1024.f);
  const float rs = rsqrtf(fmaxf(s2 * (1.f / 1024.f) - mu * mu, 0.f) + 1e-5f);
  float4 gv = ((const float4*)g)[t];
  float4 bv = ((const float4*)b)[t];
  float4 o;
  o.x = (xv.x - mu) * rs * gv.x + bv.x;
  o.y = (xv.y - mu) * rs * gv.y + bv.y;
  o.z = (xv.z - mu) * rs * gv.z + bv.z;
  o.w = (xv.w - mu) * rs * gv.w + bv.w;
  if (out1) {
    ushort4 ob;
    ob.x = f2bf(o.x); ob.y = f2bf(o.y); ob.z = f2bf(o.z); ob.w = f2bf(o.w);
    const size_t orow = (size_t)(r / grp) * stride + off + (r % grp);
    ((ushort4*)(out1 + orow * 1024))[t] = ob;
    if (out2) ((ushort4*)(out2 + (size_t)r * 1024))[t] = ob;
  }
  if (outf) ((float4*)(outf + (size_t)r * 1024))[t] = o;
}

// ---------------------------------------------------------------------------
// GEMM: C(128x128 tile) = A(MxK bf16) @ BT(NxK bf16)^T, BK=32, fp32 acc.
// Templated on MODE so each instance carries only its epilogue (reg budget:
// 64 AGPR acc + <=64 VGPR -> 4 blocks/CU with __launch_bounds__(256,4)).
// m0 from tileRows[] if given; K range [z*Ksplit,(z+1)*Ksplit) for split-K.
// MODE 1: gelu(exact) -> bf16 (ldc=N)
// MODE 3: media KV: +rbias[c]; c<1536 -> K rows; else V transposed
// MODE 4: latent QKV: q rows / K latent rows / V latent cols transposed
// MODE 5: fp32 partial store to out0 + z*4096*1024 (ldc=N)
template <int MODE>
__global__ __launch_bounds__(256, 4) void gemm_bt(
    const u16* __restrict__ A, const u16* __restrict__ BT, int N, int K,
    void* __restrict__ out0, void* __restrict__ out1, void* __restrict__ out2,
    const float* __restrict__ rbias, const int* __restrict__ tileRows,
    const int* __restrict__ tileCnt, int Ksplit) {
  int m0;
  if (tileRows) {
    if ((int)blockIdx.y >= *tileCnt) return;
    m0 = tileRows[blockIdx.y];
  } else {
    m0 = blockIdx.y * 128;
  }
  __shared__ u16 Alds[128 * 32];
  __shared__ u16 Blds[128 * 32];
  const int t = threadIdx.x;
  const int l = t & 63;
  const int w = t >> 6;
  const int n0 = blockIdx.x * 128;
  const int wr = (w >> 1) * 64;
  const int wc = (w & 1) * 64;
  const int srow = t >> 2;       // staging row (per round)
  const int scol = (t & 3) * 8;  // staging k offset
  const int frow = l & 15;       // fragment row within 16
  const int fk = (l >> 4) * 8;   // fragment k offset

  f32x4 acc[4][4] = {};

  const u16* Ap = A + (size_t)(m0 + srow) * K + scol;
  const u16* Ap2 = Ap + (size_t)64 * K;
  const u16* Bp = BT + (size_t)(n0 + srow) * K + scol;
  const u16* Bp2 = Bp + (size_t)64 * K;

  const int koff = blockIdx.z * Ksplit;
  for (int k0 = koff; k0 < koff + Ksplit; k0 += 32) {
    __syncthreads();
    gld_lds16(Ap + k0, &Alds[t * 8]);
    gld_lds16(Ap2 + k0, &Alds[2048 + t * 8]);
    gld_lds16(Bp + k0, &Blds[t * 8]);
    gld_lds16(Bp2 + k0, &Blds[2048 + t * 8]);
    __syncthreads();
    bf16x8 af[4], bfr[4];
#pragma unroll
    for (int i = 0; i < 4; ++i)
      af[i] = *(const bf16x8*)&Alds[(wr + i * 16 + frow) * 32 + fk];
#pragma unroll
    for (int j = 0; j < 4; ++j)
      bfr[j] = *(const bf16x8*)&Blds[(wc + j * 16 + frow) * 32 + fk];
#pragma unroll
    for (int i = 0; i < 4; ++i)
#pragma unroll
      for (int j = 0; j < 4; ++j) acc[i][j] = MFMA16(af[i], bfr[j], acc[i][j]);
  }

  const int col = l & 15;
  const int r4 = (l >> 4) * 4;
  const int btq = m0 / 1152;  // media tile: owning bt (MODE 3)
  const int nbase = m0 - btq * 1152;
#pragma unroll
  for (int i = 0; i < 4; ++i) {
    const int roff = wr + i * 16 + r4;  // row within tile
    const int row0 = m0 + roff;
#pragma unroll
    for (int j = 0; j < 4; ++j) {
      const int c = n0 + wc + j * 16 + col;
      if constexpr (MODE == 3) {
        const float bc = rbias[c];
        if (c < 1536) {
          u16* Kb = (u16*)out0;
#pragma unroll
          for (int r = 0; r < 4; ++r)
            Kb[(size_t)(row0 + r) * 1536 + c] = f2bf(acc[i][j][r] + bc);
        } else {
          const int cc = c - 1536;
          const int hh = cc / 96, dd = cc - hh * 96;
          ushort4 pk;
          pk.x = f2bf(acc[i][j][0] + bc);
          pk.y = f2bf(acc[i][j][1] + bc);
          pk.z = f2bf(acc[i][j][2] + bc);
          pk.w = f2bf(acc[i][j][3] + bc);
          *(ushort4*)((u16*)out1 +
                      ((size_t)(btq * 16 + hh) * 96 + dd) * 1152 + nbase + roff) = pk;
        }
      } else if constexpr (MODE == 4) {
        const int bt = row0 >> 7, ii = row0 & 127;
        if (c < 1536) {
          u16* Qb = (u16*)out0;
#pragma unroll
          for (int r = 0; r < 4; ++r)
            Qb[(size_t)(row0 + r) * 1536 + c] = f2bf(acc[i][j][r]);
        } else if (c < 3072) {
          u16* Kb = (u16*)out1;
#pragma unroll
          for (int r = 0; r < 4; ++r)
            Kb[((size_t)bt * 1152 + 1024 + ii + r) * 1536 + (c - 1536)] =
                f2bf(acc[i][j][r]);
        } else {
          const int cc = c - 3072;
          const int hh = cc / 96, dd = cc - hh * 96;
          ushort4 pk;
          pk.x = f2bf(acc[i][j][0]);
          pk.y = f2bf(acc[i][j][1]);
          pk.z = f2bf(acc[i][j][2]);
          pk.w = f2bf(acc[i][j][3]);
          *(ushort4*)((u16*)out2 +
                      ((size_t)(bt * 16 + hh) * 96 + dd) * 1152 + 1024 + ii) = pk;
        }
      } else if constexpr (MODE == 5) {
        float* O = (float*)out0 + (size_t)blockIdx.z * 4194304;
#pragma unroll
        for (int r = 0; r < 4; ++r) O[(size_t)(row0 + r) * N + c] = acc[i][j][r];
      } else {
        u16* O = (u16*)out0;
#pragma unroll
        for (int r = 0; r < 4; ++r) {
          float v = acc[i][j][r];
          if constexpr (MODE == 1) v = 0.5f * v * (1.f + erff(v * 0.70710678118f));
          O[(size_t)(row0 + r) * N + c] = f2bf(v);
        }
      }
    }
  }
}

// ---------------------------------------------------------------------------
// Flash attention over compacted KV. Block per (bt,h). 4 waves x 32 q-rows.
// Chunk 0 = latents (rows 1024..1151, always valid); then media chunks up to
// cnt_pad; compacted media slot n valid iff n < cnt (else bias -1e30).
__global__ __launch_bounds__(256) void attn_kernel(
    const u16* __restrict__ Q, const u16* __restrict__ Kb,
    const u16* __restrict__ Vt, const int* __restrict__ cnt_d,
    const int* __restrict__ cntp_d, u16* __restrict__ O) {
  const int bh = blockIdx.x;  // bt*16 + h
  const int bt = bh >> 4;
  const int h = bh & 15;
  const int bb = bt >> 2;  // batch index
  const int t = threadIdx.x, l = t & 63, w = t >> 6;
  const int lr = l & 15, lg = l >> 4;

  const int cnt = cnt_d[bb];
  const int nchunks = 1 + (cntp_d[bb] >> 7);

  __shared__ u16 Plds[4][32 * 136];  // per-wave P scratch, padded stride

  bf16x8 qf[2][3];
#pragma unroll
  for (int mt = 0; mt < 2; ++mt)
#pragma unroll
    for (int ks = 0; ks < 3; ++ks)
      qf[mt][ks] = *(const bf16x8*)(Q +
          (size_t)(bt * 128 + w * 32 + mt * 16 + lr) * 1536 + h * 96 + ks * 32 + lg * 8);

  f32x4 oa[2][6] = {};
  float m_i[2][4], l_i[2][4];
#pragma unroll
  for (int mt = 0; mt < 2; ++mt)
#pragma unroll
    for (int r = 0; r < 4; ++r) {
      m_i[mt][r] = -1e30f;
      l_i[mt][r] = 0.f;
    }

  const float L2E = 1.44269504088896f;
  u16* myP = &Plds[w][0];

  for (int ci = 0; ci < nchunks; ++ci) {
    const int nb = (ci == 0) ? 1024 : (ci - 1) * 128;

    // S = Q K^T + bias  (C-layout: col=kv idx, rows=q rows)
    f32x4 s[2][8];
#pragma unroll
    for (int nt = 0; nt < 8; ++nt) {
      f32x4 s0 = {}, s1 = {};
      const u16* kp =
          Kb + (size_t)(bt * 1152 + nb + nt * 16 + lr) * 1536 + h * 96 + lg * 8;
#pragma unroll
      for (int ks = 0; ks < 3; ++ks) {
        bf16x8 kf = *(const bf16x8*)(kp + ks * 32);
        s0 = MFMA16(qf[0][ks], kf, s0);
        s1 = MFMA16(qf[1][ks], kf, s1);
      }
      const float bn =
          (nb >= 1024) ? 0.f : (((nb + nt * 16 + lr) < cnt) ? 0.f : -1e30f);
      s[0][nt] = s0 + bn;
      s[1][nt] = s1 + bn;
    }

    // online softmax update
    float alpha[2][4];
#pragma unroll
    for (int mt = 0; mt < 2; ++mt)
#pragma unroll
      for (int r = 0; r < 4; ++r) {
        float mx = s[mt][0][r];
#pragma unroll
        for (int nt = 1; nt < 8; ++nt) mx = fmaxf(mx, s[mt][nt][r]);
#pragma unroll
        for (int d = 1; d < 16; d <<= 1) mx = fmaxf(mx, __shfl_xor(mx, d));
        const float mn = fmaxf(m_i[mt][r], mx);
        alpha[mt][r] = exp2f((m_i[mt][r] - mn) * L2E);
        m_i[mt][r] = mn;
      }

#pragma unroll
    for (int mt = 0; mt < 2; ++mt) {
      float rsum[4] = {0.f, 0.f, 0.f, 0.f};
#pragma unroll
      for (int nt = 0; nt < 8; ++nt)
#pragma unroll
        for (int r = 0; r < 4; ++r) {
          const float pv = exp2f((s[mt][nt][r] - m_i[mt][r]) * L2E);
          rsum[r] += pv;
          myP[(mt * 16 + 4 * lg + r) * 136 + nt * 16 + lr] = f2bf(pv);
        }
#pragma unroll
      for (int r = 0; r < 4; ++r) {
        float rs = rsum[r];
#pragma unroll
        for (int d = 1; d < 16; d <<= 1) rs += __shfl_xor(rs, d);
        l_i[mt][r] = alpha[mt][r] * l_i[mt][r] + rs;
      }
    }

#pragma unroll
    for (int mt = 0; mt < 2; ++mt)
#pragma unroll
      for (int dt = 0; dt < 6; ++dt)
#pragma unroll
        for (int r = 0; r < 4; ++r) oa[mt][dt][r] *= alpha[mt][r];

    __syncthreads();  // P writes drained before A-frag reads

    // O += P @ V   (A-frags from Plds, B-frags contiguous from transposed Vt)
#pragma unroll
    for (int dt = 0; dt < 6; ++dt) {
      const u16* vp = Vt + ((size_t)bh * 96 + dt * 16 + lr) * 1152 + nb + lg * 8;
#pragma unroll
      for (int ks = 0; ks < 4; ++ks) {
        bf16x8 vf = *(const bf16x8*)(vp + ks * 32);
        bf16x8 p0 = *(const bf16x8*)&myP[lr * 136 + ks * 32 + lg * 8];
        bf16x8 p1 = *(const bf16x8*)&myP[(16 + lr) * 136 + ks * 32 + lg * 8];
        oa[0][dt] = MFMA16(p0, vf, oa[0][dt]);
        oa[1][dt] = MFMA16(p1, vf, oa[1][dt]);
      }
    }
    __syncthreads();
  }

#pragma unroll
  for (int mt = 0; mt < 2; ++mt)
#pragma unroll
    for (int r = 0; r < 4; ++r) {
      const float inv = 1.f / l_i[mt][r];
#pragma unroll
      for (int dt = 0; dt < 6; ++dt)
        O[(size_t)(bt * 128 + w * 32 + mt * 16 + 4 * lg + r) * 1536 + h * 96 +
          dt * 16 + lr] = f2bf(oa[mt][dt][r] * inv);
    }
}

// ---------------------------------------------------------------------------
extern "C" void kernel_launch(void* const* d_in, const int* in_sizes, int n_in,
                              void* d_out, int out_size, void* d_ws, size_t ws_size,
                              hipStream_t stream) {
  const float* x = (const float*)d_in[0];
  const float* vmask = (const float*)d_in[1];
  const float* latents = (const float*)d_in[2];
  const float* ln_m_g = (const float*)d_in[3];
  const float* ln_m_b = (const float*)d_in[4];
  const float* ln_l_g = (const float*)d_in[5];
  const float* ln_l_b = (const float*)d_in[6];
  const float* q_w = (const float*)d_in[7];
  const float* kv_w = (const float*)d_in[8];
  const float* out_w = (const float*)d_in[9];
  const float* ff_ln_g = (const float*)d_in[10];
  const float* ff_ln_b = (const float*)d_in[11];
  const float* ff_w1 = (const float*)d_in[12];
  const float* ff_w2 = (const float*)d_in[13];
  const float* fn_g = (const float*)d_in[14];
  const float* fn_b = (const float*)d_in[15];

  char* p = (char*)d_ws;
  auto alloc = [&](size_t n) {
    char* r = p;
    p += (n + 255) & ~(size_t)255;
    return r;
  };
  u16* kvin = (u16*)alloc((size_t)36864 * 1024 * 2);   // compact LN0(x) + lm rows
  u16* lmq = (u16*)alloc((size_t)4096 * 1024 * 2);     // LN(lat) plain rows
  u16* qbuf = (u16*)alloc((size_t)4096 * 1536 * 2);    // scaled q
  u16* Kbuf = (u16*)alloc((size_t)36864 * 1536 * 2);   // K row-major (1152/bt)
  u16* Vtb = (u16*)alloc((size_t)512 * 96 * 1152 * 2); // V transposed [bh][d][n]
  u16* obuf = (u16*)alloc((size_t)4096 * 1536 * 2);    // attn out
  float* lat = (float*)alloc((size_t)4096 * 1024 * 4); // running latents fp32
  u16* kvwTm = (u16*)alloc((size_t)3072 * 1024 * 2);   // kv_w folded w/ ln_m_g
  u16* qkvT = (u16*)alloc((size_t)4608 * 1024 * 2);    // [q_w*scale ; kv_w] NxK
  u16* outwT = (u16*)alloc((size_t)1024 * 1536 * 2);
  u16* ffw1T = (u16*)alloc((size_t)4096 * 1024 * 2);
  u16* ffw2T = (u16*)alloc((size_t)1024 * 4096 * 2);
  float* rbias = (float*)alloc(3072 * 4);
  int* dest = (int*)alloc(8192 * 4);
  int* cntd = (int*)alloc(64);
  int* cntp = (int*)alloc(64);
  int* tileRows = (int*)alloc(260 * 4);
  int* tileCnt = (int*)alloc(4);
  u16* latln = lmq;           // alias: lmq dead by FF-LN time
  u16* ffh = Vtb;             // alias: Vtb dead after attention (33.5MB <= 113MB)
  float* part = (float*)Kbuf; // alias: Kbuf dead after attention (67MB <= 113MB)
  (void)in_sizes; (void)n_in; (void)out_size; (void)ws_size;

  maskscan<<<8, 256, 0, stream>>>(vmask, dest, cntd, cntp);
  tilebuild<<<1, 1, 0, stream>>>(cntp, tileRows, tileCnt);
  ln0_gather<<<32768, 256, 0, stream>>>(x, dest, kvin);
  init_lat<<<4096, 256, 0, stream>>>(latents, lat);
  // layer-0 latent LN -> kvin latent rows + lmq
  ln1024_bf16<<<4096, 256, 0, stream>>>(lat, ln_l_g, ln_l_b, kvin, 128, 1152, 1024, lmq);

  const float qscale = 0.10206207261596577f;  // 96^-0.5, folded into q weights

  for (int L = 0; L < 6; ++L) {
    // fused K=1024 weight casts: kv*g -> kvwTm, [q*s ; kv] -> qkvT, ff1 -> ffw1T
    wcast4<<<dim3(368, 32), 256, 0, stream>>>(kv_w + (size_t)L * 1024 * 3072,
                                              q_w + (size_t)L * 1024 * 1536,
                                              ff_w1 + (size_t)L * 1024 * 4096,
                                              ln_m_g + L * 1024, qscale, kvwTm,
                                              qkvT, ffw1T);
    zero3072<<<12, 256, 0, stream>>>(rbias);
    biasrow2<<<dim3(12, 16), 256, 0, stream>>>(ln_m_b + L * 1024,
                                               kv_w + (size_t)L * 1024 * 3072, rbias);
    wcastT<<<dim3(32, 48), 256, 0, stream>>>(out_w + (size_t)L * 1536 * 1024, outwT,
                                             1536, 1024, 1.f, nullptr);
    wcastT<<<dim3(32, 128), 256, 0, stream>>>(ff_w2 + (size_t)L * 4096 * 1024, ffw2T,
                                              4096, 1024, 1.f, nullptr);

    // media KV over valid tiles only: K/V = LN0x @ (g.kv_w) + b@kv_w
    gemm_bt<3><<<dim3(24, 256), 256, 0, stream>>>(kvin, kvwTm, 3072, 1024, Kbuf, Vtb,
                                                  nullptr, rbias, tileRows, tileCnt,
                                                  1024);
    // latent Q/K/V: lm @ [q_w*s ; kv_w]
    gemm_bt<4><<<dim3(36, 32), 256, 0, stream>>>(lmq, qkvT, 4608, 1024, qbuf, Kbuf,
                                                 Vtb, nullptr, nullptr, nullptr, 1024);
    // attention
    attn_kernel<<<512, 256, 0, stream>>>(qbuf, Kbuf, Vtb, cntd, cntp, obuf);
    // o @ out_w -> fp32 partials (split-K x4); then lat += sum, FF-LN -> latln
    gemm_bt<5><<<dim3(8, 32, 4), 256, 0, stream>>>(obuf, outwT, 1024, 1536, part,
                                                   nullptr, nullptr, nullptr, nullptr,
                                                   nullptr, 384);
    red4_ln<<<4096, 256, 0, stream>>>(part, lat, ff_ln_g + L * 1024,
                                      ff_ln_b + L * 1024, latln, 4096, 0, 0,
                                      nullptr, nullptr);
    // FF: hidden = gelu(latln @ w1); partials = hidden @ w2
    gemm_bt<1><<<dim3(32, 32), 256, 0, stream>>>(latln, ffw1T, 4096, 1024, ffh,
                                                 nullptr, nullptr, nullptr, nullptr,
                                                 nullptr, 1024);
    gemm_bt<5><<<dim3(8, 32, 4), 256, 0, stream>>>(ffh, ffw2T, 1024, 4096, part,
                                                   nullptr, nullptr, nullptr, nullptr,
                                                   nullptr, 1024);
    if (L < 5) {
      // lat += sum; next layer's latent LN -> kvin latent rows + lmq
      red4_ln<<<4096, 256, 0, stream>>>(part, lat, ln_l_g + (L + 1) * 1024,
                                        ln_l_b + (L + 1) * 1024, kvin, 128, 1152,
                                        1024, lmq, nullptr);
    } else {
      // lat += sum; final LN -> fp32 d_out
      red4_ln<<<4096, 256, 0, stream>>>(part, lat, fn_g, fn_b, nullptr, 1, 0, 0,
                                        nullptr, (float*)d_out);
    }
  }
}